// Round 2
// baseline (1196.974 us; speedup 1.0000x reference)
//
#include <hip/hip_runtime.h>
#include <math.h>

#define N_PTS 50000
#define V_VIEWS 500000
#define IN_MAIN 64
#define IN_MAP 16
#define IN_MOD 128
#define NC 32
#define NC_QK 8
#define SEG_EPS 1e-12f

// ws layout (bytes): didx [0,2e6) | q [2e6,3.6e6) | segmax [3.6e6,3.8e6)
//                    | segsum [3.8e6,4e6) | comp [4e6,6e6).  Total 6 MB.
// pooled accumulator lives in d_out's x_pool region (N*128 floats) — finalized
// in place by kD, so no large ws needed.

// ---------------- kernel 0: dense_idx fill + pooled (=out) zero-init ----------------
__global__ __launch_bounds__(256) void k0_setup(const int* __restrict__ csr,
                                                int* __restrict__ didx,
                                                float* __restrict__ pooled) {
    int t = blockIdx.x * blockDim.x + threadIdx.x;
    int total = gridDim.x * blockDim.x;
    if (t < N_PTS) {
        int a = csr[t], b = csr[t + 1];
        for (int v = a; v < b; ++v) didx[v] = t;
    }
    for (int i = t; i < N_PTS * IN_MOD; i += total) pooled[i] = 0.f;
}

// ---------------- kernel A: h_main -> q [N,8] ----------------
__global__ __launch_bounds__(256) void kA_main_q(
    const float* __restrict__ x_main, const float* __restrict__ W1,
    const float* __restrict__ W2, const float* __restrict__ WQ,
    const float* __restrict__ bQ, float* __restrict__ q) {
    __shared__ float W1l[IN_MAIN * NC];
    __shared__ float W2l[NC * NC];
    __shared__ float WQl[NC * NC_QK];
    __shared__ float bQl[NC_QK];
    __shared__ float h1buf[8][NC];
    __shared__ float h2buf[8][NC];
    int tid = threadIdx.x;
    for (int i = tid; i < IN_MAIN * NC; i += 256) W1l[i] = W1[i];
    for (int i = tid; i < NC * NC; i += 256) W2l[i] = W2[i];
    for (int i = tid; i < NC * NC_QK; i += 256) WQl[i] = WQ[i];
    if (tid < NC_QK) bQl[tid] = bQ[tid];
    __syncthreads();
    int g = tid >> 5, c = tid & 31;
    int p = blockIdx.x * 8 + g;
    float h1 = 0.f;
    if (p < N_PTS) {
        const float* xr = x_main + (size_t)p * IN_MAIN;
        for (int k = 0; k < IN_MAIN; ++k) h1 += xr[k] * W1l[k * NC + c];
        h1 = fmaxf(h1, 0.f);
    }
    h1buf[g][c] = h1;
    __syncthreads();
    float h2 = 0.f;
    for (int j = 0; j < NC; ++j) h2 += h1buf[g][j] * W2l[j * NC + c];
    h2buf[g][c] = h2;
    __syncthreads();
    if (c < NC_QK && p < N_PTS) {
        float acc = bQl[c];
        for (int j = 0; j < NC; ++j) acc += h2buf[g][j] * WQl[j * NC_QK + c];
        q[(size_t)p * NC_QK + c] = acc;
    }
}

// ---------------- kernel B: per-segment set_ctx, h_map, keys, comp, softmax stats ----------------
__global__ __launch_bounds__(256) void kB_seg(
    const float* __restrict__ x_map, const int* __restrict__ csr,
    const float* __restrict__ Wm1, const float* __restrict__ Wm2,
    const float* __restrict__ WK, const float* __restrict__ bK,
    const float* __restrict__ q,
    float* __restrict__ comp, float* __restrict__ segmax,
    float* __restrict__ segsum) {
    __shared__ float W1l[IN_MAP * NC];
    __shared__ float W2l[2 * NC * NC];
    __shared__ float WKl[NC * NC_QK];
    __shared__ float bKl[NC_QK];
    int tid = threadIdx.x;
    for (int i = tid; i < IN_MAP * NC; i += 256) W1l[i] = Wm1[i];
    for (int i = tid; i < 2 * NC * NC; i += 256) W2l[i] = Wm2[i];
    for (int i = tid; i < NC * NC_QK; i += 256) WKl[i] = WK[i];
    if (tid < NC_QK) bKl[tid] = bK[tid];
    __syncthreads();
    int wid = tid >> 6, lane = tid & 63;
    int seg = blockIdx.x * 4 + wid;
    if (seg >= N_PTS) return;
    int v0 = csr[seg], v1 = csr[seg + 1];
    if (v0 >= v1) {
        if (lane == 0) { segmax[seg] = 0.f; segsum[seg] = 0.f; }
        return;
    }
    int half = lane >> 5, c = lane & 31;
    // fold WK, bK with this segment's query: comp = (h_map . wq + qb)/sqrt(8)
    float wq = 0.f, qb = 0.f;
    {
        const float* qr = q + (size_t)seg * NC_QK;
        for (int j = 0; j < NC_QK; ++j) {
            float qv = qr[j];
            wq += WKl[c * NC_QK + j] * qv;
            qb += bKl[j] * qv;
        }
    }
    // pass 1: set context = segment max of relu(x_map @ Wm1)
    float ctx = 0.f;
    for (int v = v0 + half; v < v1; v += 2) {
        const float* xr = x_map + (size_t)v * IN_MAP;
        float h = 0.f;
        for (int k = 0; k < IN_MAP; ++k) h += xr[k] * W1l[k * NC + c];
        ctx = fmaxf(ctx, fmaxf(h, 0.f));
    }
    ctx = fmaxf(ctx, __shfl_xor(ctx, 32));
    // pass 2: h_map, comp, online softmax
    float mx = -__builtin_inff(), sm = 0.f;
    const float inv_sqrt = 0.35355339059327373f;
    for (int v = v0 + half; v < v1; v += 2) {
        const float* xr = x_map + (size_t)v * IN_MAP;
        float h = 0.f;
        for (int k = 0; k < IN_MAP; ++k) h += xr[k] * W1l[k * NC + c];
        h = fmaxf(h, 0.f);
        float m = 0.f;
        for (int j = 0; j < NC; ++j) m += __shfl(h, j, 32) * W2l[j * NC + c];
        for (int j = 0; j < NC; ++j) m += __shfl(ctx, j, 32) * W2l[(NC + j) * NC + c];
        m = fmaxf(m, 0.f);
        float part = m * wq;
        for (int o = 16; o > 0; o >>= 1) part += __shfl_xor(part, o, 32);
        float cm = (part + qb) * inv_sqrt;
        if (c == 0) comp[v] = cm;
        float nm = fmaxf(mx, cm);
        sm = sm * __expf(mx - nm) + __expf(cm - nm);
        mx = nm;
    }
    // combine the two halves (half1 may be empty when count is odd/1)
    {
        float om = __shfl_xor(mx, 32), os = __shfl_xor(sm, 32);
        float M = fmaxf(mx, om);
        float e1 = (mx == -__builtin_inff()) ? 0.f : __expf(mx - M);
        float e2 = (om == -__builtin_inff()) ? 0.f : __expf(om - M);
        sm = sm * e1 + os * e2;
        mx = M;
    }
    if (lane == 0) { segmax[seg] = mx; segsum[seg] = sm; }
}

// ---------------- kernel C: pooled += segment_sum(att * relu(x_mod @ Wmod1)) ----------------
#define VB 64
__global__ __launch_bounds__(512) void kC_pool(
    const float* __restrict__ x_mod, const float* __restrict__ Wmod1,
    const int* __restrict__ didx, const int* __restrict__ csr,
    const float* __restrict__ comp, const float* __restrict__ segmax,
    const float* __restrict__ segsum, float* __restrict__ pooled) {
    __shared__ float Wl[IN_MOD * IN_MOD];   // 64 KB
    __shared__ float Yl[VB][IN_MOD];        // 32 KB
    __shared__ float attl[VB];
    __shared__ int didxl[VB];
    int tid = threadIdx.x;
    for (int i = tid; i < IN_MOD * IN_MOD; i += 512) Wl[i] = Wmod1[i];
    int vbase = blockIdx.x * VB;
    if (tid < VB) {
        int v = vbase + tid;
        if (v < V_VIEWS) {
            int s = didx[v];
            didxl[tid] = s;
            attl[tid] = __expf(comp[v] - segmax[s]) / (segsum[s] + SEG_EPS);
        } else {
            didxl[tid] = N_PTS - 1;
            attl[tid] = 0.f;
        }
    }
    __syncthreads();
    // GEMM: 4 views x 4 channels per thread
    int vg = tid >> 5;   // 0..15
    int cg = tid & 31;   // 0..31
    int c0 = cg * 4;
    float acc[4][4];
    for (int i = 0; i < 4; ++i)
        for (int j = 0; j < 4; ++j) acc[i][j] = 0.f;
    const float* xrow[4];
    for (int i = 0; i < 4; ++i) {
        int v = vbase + vg * 4 + i;
        if (v >= V_VIEWS) v = V_VIEWS - 1;   // att=0 for padded rows
        xrow[i] = x_mod + (size_t)v * IN_MOD;
    }
    for (int k = 0; k < IN_MOD; ++k) {
        float4 w = *(const float4*)&Wl[k * IN_MOD + c0];
        float xv0 = xrow[0][k], xv1 = xrow[1][k], xv2 = xrow[2][k], xv3 = xrow[3][k];
        acc[0][0] += xv0 * w.x; acc[0][1] += xv0 * w.y; acc[0][2] += xv0 * w.z; acc[0][3] += xv0 * w.w;
        acc[1][0] += xv1 * w.x; acc[1][1] += xv1 * w.y; acc[1][2] += xv1 * w.z; acc[1][3] += xv1 * w.w;
        acc[2][0] += xv2 * w.x; acc[2][1] += xv2 * w.y; acc[2][2] += xv2 * w.z; acc[2][3] += xv2 * w.w;
        acc[3][0] += xv3 * w.x; acc[3][1] += xv3 * w.y; acc[3][2] += xv3 * w.z; acc[3][3] += xv3 * w.w;
    }
    for (int i = 0; i < 4; ++i) {
        int r = vg * 4 + i;
        float a = attl[r];
        for (int j = 0; j < 4; ++j)
            Yl[r][c0 + j] = fmaxf(acc[i][j], 0.f) * a;
    }
    __syncthreads();
    // per-channel segmented scan over the 64 rows
    if (tid < IN_MOD) {
        int c = tid;
        float s_acc = 0.f;
        int cur = didxl[0];
        for (int r = 0; r < VB; ++r) {
            int s = didxl[r];
            if (s != cur) {
                int a = csr[cur], b = csr[cur + 1];
                if (a >= vbase && b <= vbase + VB)
                    pooled[(size_t)cur * IN_MOD + c] = s_acc;
                else
                    atomicAdd(&pooled[(size_t)cur * IN_MOD + c], s_acc);
                s_acc = 0.f; cur = s;
            }
            s_acc += Yl[r][c];
        }
        int a = csr[cur], b = csr[cur + 1];
        if (a >= vbase && b <= vbase + VB)
            pooled[(size_t)cur * IN_MOD + c] = s_acc;
        else
            atomicAdd(&pooled[(size_t)cur * IN_MOD + c], s_acc);
    }
}

// ---------------- kernel D: out = (pooled @ Wmod2) * gate, in place; x_seen ----------------
// pooled IS out's x_pool region: stage each row through LDS before overwriting.
__global__ __launch_bounds__(256) void kD_final(
    const float* __restrict__ Wmod2,
    const float* __restrict__ segmax, const int* __restrict__ csr,
    const float* __restrict__ g_w, const float* __restrict__ g_b,
    float* __restrict__ out) {
    __shared__ float Wl[IN_MOD * IN_MOD];
    __shared__ float rowl[2][IN_MOD];
    int tid = threadIdx.x;
    for (int i = tid; i < IN_MOD * IN_MOD; i += 256) Wl[i] = Wmod2[i];
    __syncthreads();
    float gw = g_w[0], gb = g_b[0];
    int h = tid >> 7, c = tid & 127;
    // N_PTS is even and s0 is even, so s = s0 + h < N_PTS whenever s0 < N_PTS.
    for (int s0 = blockIdx.x * 2; s0 < N_PTS; s0 += gridDim.x * 2) {
        int s = s0 + h;
        rowl[h][c] = out[(size_t)s * IN_MOD + c];
        __syncthreads();
        float acc = 0.f;
        for (int k = 0; k < IN_MOD; ++k) acc += rowl[h][k] * Wl[k * IN_MOD + c];
        bool ne = csr[s + 1] > csr[s];
        float gin = ne ? segmax[s] : 0.f;
        float gate = tanhf(fmaxf(gw * gin + gb, 0.f));
        out[(size_t)s * IN_MOD + c] = acc * gate;
        if (c == 0) out[(size_t)N_PTS * IN_MOD + s] = ne ? 1.f : 0.f;
        __syncthreads();
    }
}

extern "C" void kernel_launch(void* const* d_in, const int* in_sizes, int n_in,
                              void* d_out, int out_size, void* d_ws, size_t ws_size,
                              hipStream_t stream) {
    (void)in_sizes; (void)n_in; (void)out_size; (void)ws_size;
    const float* x_main = (const float*)d_in[0];
    const float* x_mod  = (const float*)d_in[1];
    const float* x_map  = (const float*)d_in[2];
    const int*   csr    = (const int*)d_in[3];
    const float* W_main1 = (const float*)d_in[4];
    const float* W_main2 = (const float*)d_in[5];
    const float* W_map1  = (const float*)d_in[6];
    const float* W_map2  = (const float*)d_in[7];
    const float* W_mod1  = (const float*)d_in[8];
    const float* W_mod2  = (const float*)d_in[9];
    const float* WQ = (const float*)d_in[10];
    const float* bQ = (const float*)d_in[11];
    const float* WK = (const float*)d_in[12];
    const float* bK = (const float*)d_in[13];
    const float* g_w = (const float*)d_in[14];
    const float* g_b = (const float*)d_in[15];
    float* out = (float*)d_out;

    char* ws = (char*)d_ws;
    int*   didx   = (int*)ws;                      // V ints      [0, 2.0 MB)
    float* q      = (float*)(ws + 2000000);        // N*8         [2.0, 3.6 MB)
    float* segmax = (float*)(ws + 3600000);        // N           [3.6, 3.8 MB)
    float* segsum = (float*)(ws + 3800000);        // N           [3.8, 4.0 MB)
    float* comp   = (float*)(ws + 4000000);        // V           [4.0, 6.0 MB)
    float* pooled = out;                           // N*128 floats of d_out

    k0_setup<<<196, 256, 0, stream>>>(csr, didx, pooled);
    kA_main_q<<<(N_PTS + 7) / 8, 256, 0, stream>>>(x_main, W_main1, W_main2, WQ, bQ, q);
    kB_seg<<<(N_PTS + 3) / 4, 256, 0, stream>>>(x_map, csr, W_map1, W_map2, WK, bK, q,
                                                comp, segmax, segsum);
    kC_pool<<<(V_VIEWS + VB - 1) / VB, 512, 0, stream>>>(x_mod, W_mod1, didx, csr,
                                                         comp, segmax, segsum, pooled);
    kD_final<<<2048, 256, 0, stream>>>(W_mod2, segmax, csr, g_w, g_b, out);
}

// Round 3
// 666.392 us; speedup vs baseline: 1.7962x; 1.7962x over previous
//
#include <hip/hip_runtime.h>
#include <math.h>

#define N_PTS 50000
#define V_VIEWS 500000
#define IN_MAIN 64
#define IN_MAP 16
#define IN_MOD 128
#define NC 32
#define NC_QK 8
#define SEG_EPS 1e-12f

typedef short bf16x8 __attribute__((ext_vector_type(8)));
typedef float f32x4 __attribute__((ext_vector_type(4)));

static __device__ __forceinline__ short f2bf(float x) {
    union { float f; unsigned u; } v; v.f = x;
    unsigned r = v.u + 0x7fffu + ((v.u >> 16) & 1u);   // RNE
    return (short)(r >> 16);
}

// ws layout (bytes):
//   didx    [ 0.0, 2.0 MB)  V int
//   wq      [ 2.0, 8.4 MB)  N*32 f32   (WK @ q per segment)
//   qb      [ 8.4, 8.6 MB)  N f32      (bK . q per segment)
//   ctxW2b  [ 8.6,15.0 MB)  N*32 f32   (set_ctx @ W_map2[32:64] per segment)
//   comp    [15.0,17.0 MB)  V f32      (comp, overwritten in place with att)
//   segmax  [17.0,17.2 MB)  N f32
// pooled accumulator = d_out's x_pool region (N*128 f32), finalized in place by kD.

// ---------------- k0: dense_idx fill + pooled (=out) zero-init ----------------
__global__ __launch_bounds__(256) void k0_setup(const int* __restrict__ csr,
                                                int* __restrict__ didx,
                                                float* __restrict__ pooled) {
    int t = blockIdx.x * blockDim.x + threadIdx.x;
    int total = gridDim.x * blockDim.x;
    if (t < N_PTS) {
        int a = csr[t], b = csr[t + 1];
        for (int v = a; v < b; ++v) didx[v] = t;
    }
    for (int i = t; i < N_PTS * IN_MOD; i += total) pooled[i] = 0.f;
}

// ---------------- kA: x_main -> h_main -> q -> wq[N,32], qb[N] ----------------
__global__ __launch_bounds__(256) void kA_main_q(
    const float* __restrict__ x_main, const float* __restrict__ W1,
    const float* __restrict__ W2, const float* __restrict__ WQ,
    const float* __restrict__ bQ, const float* __restrict__ WK,
    const float* __restrict__ bK,
    float* __restrict__ wq, float* __restrict__ qb) {
    __shared__ float W1l[IN_MAIN * NC];
    __shared__ float W2l[NC * NC];
    __shared__ float WQl[NC * NC_QK];
    __shared__ float WKl[NC * NC_QK];
    __shared__ float bQl[NC_QK];
    __shared__ float bKl[NC_QK];
    __shared__ float h1buf[8][NC];
    __shared__ float h2buf[8][NC];
    __shared__ float qbuf[8][NC_QK];
    int tid = threadIdx.x;
    for (int i = tid; i < IN_MAIN * NC; i += 256) W1l[i] = W1[i];
    for (int i = tid; i < NC * NC; i += 256) W2l[i] = W2[i];
    for (int i = tid; i < NC * NC_QK; i += 256) WQl[i] = WQ[i];
    for (int i = tid; i < NC * NC_QK; i += 256) WKl[i] = WK[i];
    if (tid < NC_QK) { bQl[tid] = bQ[tid]; bKl[tid] = bK[tid]; }
    __syncthreads();
    int g = tid >> 5, c = tid & 31;
    int p = blockIdx.x * 8 + g;
    float h1 = 0.f;
    if (p < N_PTS) {
        const float* xr = x_main + (size_t)p * IN_MAIN;
        for (int k = 0; k < IN_MAIN; ++k) h1 += xr[k] * W1l[k * NC + c];
        h1 = fmaxf(h1, 0.f);
    }
    h1buf[g][c] = h1;
    __syncthreads();
    float h2 = 0.f;
    for (int j = 0; j < NC; ++j) h2 += h1buf[g][j] * W2l[j * NC + c];
    h2buf[g][c] = h2;
    __syncthreads();
    if (c < NC_QK) {
        float acc = bQl[c];
        for (int j = 0; j < NC; ++j) acc += h2buf[g][j] * WQl[j * NC_QK + c];
        qbuf[g][c] = acc;
    }
    __syncthreads();
    if (p < N_PTS) {
        float w = 0.f;
        for (int j = 0; j < NC_QK; ++j) w += WKl[c * NC_QK + j] * qbuf[g][j];
        wq[(size_t)p * NC + c] = w;
        if (c == 0) {
            float b = 0.f;
            for (int j = 0; j < NC_QK; ++j) b += bKl[j] * qbuf[g][j];
            qb[p] = b;
        }
    }
}

// ---------------- kB2: per-segment ctx = segmax(relu(x_map@W1)); ctxW2b = ctx @ W2b ----------------
__global__ __launch_bounds__(256) void kB2_ctx(
    const float* __restrict__ x_map, const int* __restrict__ csr,
    const float* __restrict__ Wm1, const float* __restrict__ Wm2,
    float* __restrict__ ctxW2b) {
    __shared__ float W1l[IN_MAP * NC];        // 2 KB
    __shared__ float W2bl[NC * NC];           // 4 KB (rows 32..63 of W_map2)
    int tid = threadIdx.x;
    for (int i = tid; i < IN_MAP * NC; i += 256) W1l[i] = Wm1[i];
    for (int i = tid; i < NC * NC; i += 256) W2bl[i] = Wm2[NC * NC + i];
    __syncthreads();
    int wid = tid >> 6, lane = tid & 63;
    int seg = blockIdx.x * 4 + wid;
    if (seg >= N_PTS) return;
    int v0 = csr[seg], v1 = csr[seg + 1];
    int half = lane >> 5, c = lane & 31;
    float ctx = 0.f;
    for (int v = v0 + half; v < v1; v += 2) {
        const float4* xr = (const float4*)(x_map + (size_t)v * IN_MAP);
        float4 a = xr[0], b = xr[1], d = xr[2], e = xr[3];
        float h = a.x * W1l[0 * NC + c] + a.y * W1l[1 * NC + c]
                + a.z * W1l[2 * NC + c] + a.w * W1l[3 * NC + c]
                + b.x * W1l[4 * NC + c] + b.y * W1l[5 * NC + c]
                + b.z * W1l[6 * NC + c] + b.w * W1l[7 * NC + c]
                + d.x * W1l[8 * NC + c] + d.y * W1l[9 * NC + c]
                + d.z * W1l[10 * NC + c] + d.w * W1l[11 * NC + c]
                + e.x * W1l[12 * NC + c] + e.y * W1l[13 * NC + c]
                + e.z * W1l[14 * NC + c] + e.w * W1l[15 * NC + c];
        ctx = fmaxf(ctx, h);
    }
    ctx = fmaxf(ctx, __shfl_xor(ctx, 32));
    // ctxW2b[c'] = sum_c ctx_c * W2b[c][c']   (ctx_c held by lane c, c in 0..31)
    float val = 0.f;
    for (int j = 0; j < NC; ++j) val += __shfl(ctx, j, 64) * W2bl[j * NC + c];
    if (half == 0) ctxW2b[(size_t)seg * NC + c] = val;
}

// ---------------- kB3: dense comp over views ----------------
__global__ __launch_bounds__(256) void kB3_comp(
    const float* __restrict__ x_map, const int* __restrict__ didx,
    const float* __restrict__ Wm1, const float* __restrict__ Wm2,
    const float* __restrict__ ctxW2b, const float* __restrict__ wq,
    const float* __restrict__ qb, float* __restrict__ comp) {
    __shared__ float W1l[IN_MAP * NC];        // 2 KB
    __shared__ float W2al[NC * NC];           // 4 KB (rows 0..31 of W_map2)
    int tid = threadIdx.x;
    for (int i = tid; i < IN_MAP * NC; i += 256) W1l[i] = Wm1[i];
    for (int i = tid; i < NC * NC; i += 256) W2al[i] = Wm2[i];
    __syncthreads();
    int g = tid >> 5, c = tid & 31;
    const float inv_sqrt = 0.35355339059327373f;
    int vbase = (blockIdx.x * 8 + g) * 8;
    for (int vi = 0; vi < 8; ++vi) {
        int v = vbase + vi;
        if (v >= V_VIEWS) break;
        int s = didx[v];
        float xv = (c < IN_MAP) ? x_map[(size_t)v * IN_MAP + c] : 0.f;
        float h = 0.f;
        for (int k = 0; k < IN_MAP; ++k) h += __shfl(xv, k, 32) * W1l[k * NC + c];
        h = fmaxf(h, 0.f);
        float m = ctxW2b[(size_t)s * NC + c];
        for (int k = 0; k < NC; ++k) m += __shfl(h, k, 32) * W2al[k * NC + c];
        m = fmaxf(m, 0.f);
        float part = m * wq[(size_t)s * NC + c];
        for (int o = 16; o > 0; o >>= 1) part += __shfl_xor(part, o, 32);
        if (c == 0) comp[v] = (part + qb[s]) * inv_sqrt;
    }
}

// ---------------- kB4: per-segment softmax; comp -> att in place; segmax out ----------------
__global__ __launch_bounds__(256) void kB4_att(
    float* __restrict__ comp, const int* __restrict__ csr,
    float* __restrict__ segmax) {
    int wid = threadIdx.x >> 6, lane = threadIdx.x & 63;
    int seg = blockIdx.x * 4 + wid;
    if (seg >= N_PTS) return;
    int v0 = csr[seg], v1 = csr[seg + 1];
    if (v0 >= v1) {
        if (lane == 0) segmax[seg] = 0.f;
        return;
    }
    float mx = -__builtin_inff();
    for (int v = v0 + lane; v < v1; v += 64) mx = fmaxf(mx, comp[v]);
    for (int o = 32; o > 0; o >>= 1) mx = fmaxf(mx, __shfl_xor(mx, o));
    float sm = 0.f;
    for (int v = v0 + lane; v < v1; v += 64) sm += __expf(comp[v] - mx);
    for (int o = 32; o > 0; o >>= 1) sm += __shfl_xor(sm, o);
    float inv = 1.f / (sm + SEG_EPS);
    for (int v = v0 + lane; v < v1; v += 64) comp[v] = __expf(comp[v] - mx) * inv;
    if (lane == 0) segmax[seg] = mx;
}

// ---------------- kC: pooled += segsum(att * relu(x_mod @ Wmod1))  [bf16 MFMA] ----------------
#define VB 64
__global__ __launch_bounds__(256) void kC_pool(
    const float* __restrict__ x_mod, const float* __restrict__ Wmod1,
    const int* __restrict__ didx, const int* __restrict__ csr,
    const float* __restrict__ att, float* __restrict__ pooled) {
    __shared__ short W1t[IN_MOD * IN_MOD];        // 32 KB, transposed [c][k], k-block XOR swizzled
    __shared__ float Yl[VB * 132];                // 33 KB, row stride 132 (bank-decorrelated)
    __shared__ float attl[VB];
    __shared__ int didxl[VB];
    int tid = threadIdx.x;
    int vbase = blockIdx.x * VB;
    // stage W_mod1 transposed + bf16 + swizzle: elem (k,c) -> W1t[c*128 + ((k>>3)^(c&7))*8 + (k&7)]
    for (int i = tid; i < IN_MOD * IN_MOD; i += 256) {
        int k = i >> 7, c = i & 127;
        W1t[c * 128 + (((k >> 3) ^ (c & 7)) << 3) + (k & 7)] = f2bf(Wmod1[i]);
    }
    if (tid < VB) {
        int v = vbase + tid;
        if (v < V_VIEWS) {
            didxl[tid] = didx[v];
            attl[tid] = att[v];
        } else {
            didxl[tid] = didx[V_VIEWS - 1];
            attl[tid] = 0.f;
        }
    }
    __syncthreads();

    int w = tid >> 6, lane = tid & 63;
    int row16 = lane & 15;          // view row within wave tile
    int kq = lane >> 4;             // 0..3
    int k0 = kq << 3;               // lane's 8-elem k chunk base within K=32
    f32x4 acc[8];
    for (int j = 0; j < 8; ++j) acc[j] = (f32x4){0.f, 0.f, 0.f, 0.f};

    int v = vbase + w * 16 + row16;
    if (v >= V_VIEWS) v = V_VIEWS - 1;            // att=0 handles padding
    const float* xp = x_mod + (size_t)v * IN_MOD;

#pragma unroll
    for (int kk = 0; kk < 4; ++kk) {
        float4 x0 = *(const float4*)(xp + kk * 32 + k0);
        float4 x1 = *(const float4*)(xp + kk * 32 + k0 + 4);
        bf16x8 a;
        a[0] = f2bf(x0.x); a[1] = f2bf(x0.y); a[2] = f2bf(x0.z); a[3] = f2bf(x0.w);
        a[4] = f2bf(x1.x); a[5] = f2bf(x1.y); a[6] = f2bf(x1.z); a[7] = f2bf(x1.w);
#pragma unroll
        for (int j = 0; j < 8; ++j) {
            int ch = j * 16 + row16;
            bf16x8 b = *(const bf16x8*)&W1t[ch * 128 + (((kk * 4 + kq) ^ (ch & 7)) << 3)];
            acc[j] = __builtin_amdgcn_mfma_f32_16x16x32_bf16(a, b, acc[j], 0, 0, 0);
        }
    }
    // epilogue: relu, att-scale, stage to LDS  (C/D: col=lane&15, row=(lane>>4)*4+r)
#pragma unroll
    for (int j = 0; j < 8; ++j) {
        int ch = j * 16 + row16;
        int rbase = w * 16 + (kq << 2);
#pragma unroll
        for (int r = 0; r < 4; ++r) {
            int rw = rbase + r;
            Yl[rw * 132 + ch] = fmaxf(acc[j][r], 0.f) * attl[rw];
        }
    }
    __syncthreads();
    // segmented scan over 64 rows, one thread per channel
    if (tid < IN_MOD) {
        int c = tid;
        float s_acc = 0.f;
        int cur = didxl[0];
        for (int r = 0; r < VB; ++r) {
            int s = didxl[r];
            if (s != cur) {
                if (csr[cur] >= vbase && csr[cur + 1] <= vbase + VB)
                    pooled[(size_t)cur * IN_MOD + c] = s_acc;
                else
                    atomicAdd(&pooled[(size_t)cur * IN_MOD + c], s_acc);
                s_acc = 0.f; cur = s;
            }
            s_acc += Yl[r * 132 + c];
        }
        if (csr[cur] >= vbase && csr[cur + 1] <= vbase + VB)
            pooled[(size_t)cur * IN_MOD + c] = s_acc;
        else
            atomicAdd(&pooled[(size_t)cur * IN_MOD + c], s_acc);
    }
}

// ---------------- kD: out = (pooled @ Wmod2) * gate, in place; x_seen ----------------
__global__ __launch_bounds__(256) void kD_final(
    const float* __restrict__ Wmod2,
    const float* __restrict__ segmax, const int* __restrict__ csr,
    const float* __restrict__ g_w, const float* __restrict__ g_b,
    float* __restrict__ out) {
    __shared__ float Wl[IN_MOD * IN_MOD];
    __shared__ float rowl[2][IN_MOD];
    int tid = threadIdx.x;
    for (int i = tid; i < IN_MOD * IN_MOD; i += 256) Wl[i] = Wmod2[i];
    __syncthreads();
    float gw = g_w[0], gb = g_b[0];
    int h = tid >> 7, c = tid & 127;
    for (int s0 = blockIdx.x * 2; s0 < N_PTS; s0 += gridDim.x * 2) {
        int s = s0 + h;
        rowl[h][c] = out[(size_t)s * IN_MOD + c];
        __syncthreads();
        float acc = 0.f;
        for (int k = 0; k < IN_MOD; ++k) acc += rowl[h][k] * Wl[k * IN_MOD + c];
        bool ne = csr[s + 1] > csr[s];
        float gin = ne ? segmax[s] : 0.f;
        float gate = tanhf(fmaxf(gw * gin + gb, 0.f));
        out[(size_t)s * IN_MOD + c] = acc * gate;
        if (c == 0) out[(size_t)N_PTS * IN_MOD + s] = ne ? 1.f : 0.f;
        __syncthreads();
    }
}

extern "C" void kernel_launch(void* const* d_in, const int* in_sizes, int n_in,
                              void* d_out, int out_size, void* d_ws, size_t ws_size,
                              hipStream_t stream) {
    (void)in_sizes; (void)n_in; (void)out_size; (void)ws_size;
    const float* x_main = (const float*)d_in[0];
    const float* x_mod  = (const float*)d_in[1];
    const float* x_map  = (const float*)d_in[2];
    const int*   csr    = (const int*)d_in[3];
    const float* W_main1 = (const float*)d_in[4];
    const float* W_main2 = (const float*)d_in[5];
    const float* W_map1  = (const float*)d_in[6];
    const float* W_map2  = (const float*)d_in[7];
    const float* W_mod1  = (const float*)d_in[8];
    const float* W_mod2  = (const float*)d_in[9];
    const float* WQ = (const float*)d_in[10];
    const float* bQ = (const float*)d_in[11];
    const float* WK = (const float*)d_in[12];
    const float* bK = (const float*)d_in[13];
    const float* g_w = (const float*)d_in[14];
    const float* g_b = (const float*)d_in[15];
    float* out = (float*)d_out;

    char* ws = (char*)d_ws;
    int*   didx   = (int*)ws;                       // [ 0.0,  2.0 MB)
    float* wq     = (float*)(ws + 2000000);         // [ 2.0,  8.4 MB)
    float* qb     = (float*)(ws + 8400000);         // [ 8.4,  8.6 MB)
    float* ctxW2b = (float*)(ws + 8600000);         // [ 8.6, 15.0 MB)
    float* comp   = (float*)(ws + 15000000);        // [15.0, 17.0 MB)  comp -> att
    float* segmax = (float*)(ws + 17000000);        // [17.0, 17.2 MB)
    float* pooled = out;                            // N*128 floats of d_out

    k0_setup<<<512, 256, 0, stream>>>(csr, didx, pooled);
    kA_main_q<<<(N_PTS + 7) / 8, 256, 0, stream>>>(x_main, W_main1, W_main2, WQ, bQ,
                                                   WK, bK, wq, qb);
    kB2_ctx<<<(N_PTS + 3) / 4, 256, 0, stream>>>(x_map, csr, W_map1, W_map2, ctxW2b);
    kB3_comp<<<(V_VIEWS + 63) / 64, 256, 0, stream>>>(x_map, didx, W_map1, W_map2,
                                                      ctxW2b, wq, qb, comp);
    kB4_att<<<(N_PTS + 3) / 4, 256, 0, stream>>>(comp, csr, segmax);
    kC_pool<<<(V_VIEWS + VB - 1) / VB, 256, 0, stream>>>(x_mod, W_mod1, didx, csr,
                                                         comp, pooled);
    kD_final<<<2048, 256, 0, stream>>>(W_mod2, segmax, csr, g_w, g_b, out);
}

// Round 4
// 567.504 us; speedup vs baseline: 2.1092x; 1.1743x over previous
//
#include <hip/hip_runtime.h>
#include <math.h>

#define N_PTS 50000
#define V_VIEWS 500000
#define IN_MAIN 64
#define IN_MAP 16
#define IN_MOD 128
#define NC 32
#define NC_QK 8
#define SEG_EPS 1e-12f

typedef short bf16x8 __attribute__((ext_vector_type(8)));
typedef float f32x4 __attribute__((ext_vector_type(4)));

static __device__ __forceinline__ short f2bf(float x) {
    union { float f; unsigned u; } v; v.f = x;
    unsigned r = v.u + 0x7fffu + ((v.u >> 16) & 1u);   // RNE
    return (short)(r >> 16);
}

// ws layout (bytes):
//   didx    [ 0.0, 2.0 MB)  V int
//   wq      [ 2.0, 8.4 MB)  N*32 f32
//   qb      [ 8.4, 8.6 MB)  N f32
//   ctxW2b  [ 8.6,15.0 MB)  N*32 f32
//   comp    [15.0,17.0 MB)  V f32 (-> att in place)
//   segmax  [17.0,17.2 MB)  N f32
//   Wf      [17.2,17.24 MB) 16384 bf16 — W_mod1 in MFMA-fragment-linear layout
// pooled accumulator = d_out's x_pool region, finalized in place by kD.

// ---------------- k0: didx fill + pooled zero + Wf build ----------------
// Wf layout: frag (kk in 0..3, j in 0..7), lane l in 0..63, elem e in 0..7:
//   Wf[((kk*8+j)*64 + l)*8 + e] = bf16( W_mod1[ (kk*32 + (l>>4)*8 + e) * 128 + (j*16 + (l&15)) ] )
// so kC's lane l loads its B fragment as ONE coalesced 16B chunk.
__global__ __launch_bounds__(256) void k0_setup(const int* __restrict__ csr,
                                                const float* __restrict__ Wmod1,
                                                int* __restrict__ didx,
                                                float* __restrict__ pooled,
                                                short* __restrict__ Wf) {
    int t = blockIdx.x * blockDim.x + threadIdx.x;
    int total = gridDim.x * blockDim.x;
    if (t < N_PTS) {
        int a = csr[t], b = csr[t + 1];
        for (int v = a; v < b; ++v) didx[v] = t;
    }
    for (int i = t; i < N_PTS * IN_MOD; i += total) pooled[i] = 0.f;
    for (int i = t; i < IN_MOD * IN_MOD; i += total) {
        int e = i & 7, l = (i >> 3) & 63, j = (i >> 9) & 7, kk = i >> 12;
        int k = kk * 32 + ((l >> 4) << 3) + e;
        int ch = (j << 4) + (l & 15);
        Wf[i] = f2bf(Wmod1[k * IN_MOD + ch]);
    }
}

// ---------------- kA: x_main -> h_main -> q -> wq[N,32], qb[N] ----------------
__global__ __launch_bounds__(256) void kA_main_q(
    const float* __restrict__ x_main, const float* __restrict__ W1,
    const float* __restrict__ W2, const float* __restrict__ WQ,
    const float* __restrict__ bQ, const float* __restrict__ WK,
    const float* __restrict__ bK,
    float* __restrict__ wq, float* __restrict__ qb) {
    __shared__ float W1l[IN_MAIN * NC];
    __shared__ float W2l[NC * NC];
    __shared__ float WQl[NC * NC_QK];
    __shared__ float WKl[NC * NC_QK];
    __shared__ float bQl[NC_QK];
    __shared__ float bKl[NC_QK];
    __shared__ float h1buf[8][NC];
    __shared__ float h2buf[8][NC];
    __shared__ float qbuf[8][NC_QK];
    int tid = threadIdx.x;
    for (int i = tid; i < IN_MAIN * NC; i += 256) W1l[i] = W1[i];
    for (int i = tid; i < NC * NC; i += 256) W2l[i] = W2[i];
    for (int i = tid; i < NC * NC_QK; i += 256) WQl[i] = WQ[i];
    for (int i = tid; i < NC * NC_QK; i += 256) WKl[i] = WK[i];
    if (tid < NC_QK) { bQl[tid] = bQ[tid]; bKl[tid] = bK[tid]; }
    __syncthreads();
    int g = tid >> 5, c = tid & 31;
    int p = blockIdx.x * 8 + g;
    float h1 = 0.f;
    if (p < N_PTS) {
        const float* xr = x_main + (size_t)p * IN_MAIN;
        for (int k = 0; k < IN_MAIN; ++k) h1 += xr[k] * W1l[k * NC + c];
        h1 = fmaxf(h1, 0.f);
    }
    h1buf[g][c] = h1;
    __syncthreads();
    float h2 = 0.f;
    for (int j = 0; j < NC; ++j) h2 += h1buf[g][j] * W2l[j * NC + c];
    h2buf[g][c] = h2;
    __syncthreads();
    if (c < NC_QK) {
        float acc = bQl[c];
        for (int j = 0; j < NC; ++j) acc += h2buf[g][j] * WQl[j * NC_QK + c];
        qbuf[g][c] = acc;
    }
    __syncthreads();
    if (p < N_PTS) {
        float w = 0.f;
        for (int j = 0; j < NC_QK; ++j) w += WKl[c * NC_QK + j] * qbuf[g][j];
        wq[(size_t)p * NC + c] = w;
        if (c == 0) {
            float b = 0.f;
            for (int j = 0; j < NC_QK; ++j) b += bKl[j] * qbuf[g][j];
            qb[p] = b;
        }
    }
}

// ---------------- kB2: per-segment ctx = segmax(relu(x_map@W1)); ctxW2b = ctx @ W2b ----------------
__global__ __launch_bounds__(256) void kB2_ctx(
    const float* __restrict__ x_map, const int* __restrict__ csr,
    const float* __restrict__ Wm1, const float* __restrict__ Wm2,
    float* __restrict__ ctxW2b) {
    __shared__ float W1l[IN_MAP * NC];
    __shared__ float W2bl[NC * NC];
    int tid = threadIdx.x;
    for (int i = tid; i < IN_MAP * NC; i += 256) W1l[i] = Wm1[i];
    for (int i = tid; i < NC * NC; i += 256) W2bl[i] = Wm2[NC * NC + i];
    __syncthreads();
    int wid = tid >> 6, lane = tid & 63;
    int seg = blockIdx.x * 4 + wid;
    if (seg >= N_PTS) return;
    int v0 = csr[seg], v1 = csr[seg + 1];
    int half = lane >> 5, c = lane & 31;
    float ctx = 0.f;
    for (int v = v0 + half; v < v1; v += 2) {
        const float4* xr = (const float4*)(x_map + (size_t)v * IN_MAP);
        float4 a = xr[0], b = xr[1], d = xr[2], e = xr[3];
        float h = a.x * W1l[0 * NC + c] + a.y * W1l[1 * NC + c]
                + a.z * W1l[2 * NC + c] + a.w * W1l[3 * NC + c]
                + b.x * W1l[4 * NC + c] + b.y * W1l[5 * NC + c]
                + b.z * W1l[6 * NC + c] + b.w * W1l[7 * NC + c]
                + d.x * W1l[8 * NC + c] + d.y * W1l[9 * NC + c]
                + d.z * W1l[10 * NC + c] + d.w * W1l[11 * NC + c]
                + e.x * W1l[12 * NC + c] + e.y * W1l[13 * NC + c]
                + e.z * W1l[14 * NC + c] + e.w * W1l[15 * NC + c];
        ctx = fmaxf(ctx, h);
    }
    ctx = fmaxf(ctx, __shfl_xor(ctx, 32));
    float val = 0.f;
    for (int j = 0; j < NC; ++j) val += __shfl(ctx, j, 64) * W2bl[j * NC + c];
    if (half == 0) ctxW2b[(size_t)seg * NC + c] = val;
}

// ---------------- kB3: dense comp over views ----------------
__global__ __launch_bounds__(256) void kB3_comp(
    const float* __restrict__ x_map, const int* __restrict__ didx,
    const float* __restrict__ Wm1, const float* __restrict__ Wm2,
    const float* __restrict__ ctxW2b, const float* __restrict__ wq,
    const float* __restrict__ qb, float* __restrict__ comp) {
    __shared__ float W1l[IN_MAP * NC];
    __shared__ float W2al[NC * NC];
    int tid = threadIdx.x;
    for (int i = tid; i < IN_MAP * NC; i += 256) W1l[i] = Wm1[i];
    for (int i = tid; i < NC * NC; i += 256) W2al[i] = Wm2[i];
    __syncthreads();
    int g = tid >> 5, c = tid & 31;
    const float inv_sqrt = 0.35355339059327373f;
    int vbase = (blockIdx.x * 8 + g) * 8;
    for (int vi = 0; vi < 8; ++vi) {
        int v = vbase + vi;
        if (v >= V_VIEWS) break;
        int s = didx[v];
        float xv = (c < IN_MAP) ? x_map[(size_t)v * IN_MAP + c] : 0.f;
        float h = 0.f;
        for (int k = 0; k < IN_MAP; ++k) h += __shfl(xv, k, 32) * W1l[k * NC + c];
        h = fmaxf(h, 0.f);
        float m = ctxW2b[(size_t)s * NC + c];
        for (int k = 0; k < NC; ++k) m += __shfl(h, k, 32) * W2al[k * NC + c];
        m = fmaxf(m, 0.f);
        float part = m * wq[(size_t)s * NC + c];
        for (int o = 16; o > 0; o >>= 1) part += __shfl_xor(part, o, 32);
        if (c == 0) comp[v] = (part + qb[s]) * inv_sqrt;
    }
}

// ---------------- kB4: per-segment softmax; comp -> att in place; segmax out ----------------
__global__ __launch_bounds__(256) void kB4_att(
    float* __restrict__ comp, const int* __restrict__ csr,
    float* __restrict__ segmax) {
    int wid = threadIdx.x >> 6, lane = threadIdx.x & 63;
    int seg = blockIdx.x * 4 + wid;
    if (seg >= N_PTS) return;
    int v0 = csr[seg], v1 = csr[seg + 1];
    if (v0 >= v1) {
        if (lane == 0) segmax[seg] = 0.f;
        return;
    }
    float mx = -__builtin_inff();
    for (int v = v0 + lane; v < v1; v += 64) mx = fmaxf(mx, comp[v]);
    for (int o = 32; o > 0; o >>= 1) mx = fmaxf(mx, __shfl_xor(mx, o));
    float sm = 0.f;
    for (int v = v0 + lane; v < v1; v += 64) sm += __expf(comp[v] - mx);
    for (int o = 32; o > 0; o >>= 1) sm += __shfl_xor(sm, o);
    float inv = 1.f / (sm + SEG_EPS);
    for (int v = v0 + lane; v < v1; v += 64) comp[v] = __expf(comp[v] - mx) * inv;
    if (lane == 0) segmax[seg] = mx;
}

// ---------------- kC: pooled += segsum(att * relu(x_mod @ Wmod1))  [bf16 MFMA] ----------------
// B fragments come straight from L2-resident fragment-linear Wf (no LDS W staging).
#define VB 64
__global__ __launch_bounds__(256) void kC_pool(
    const float* __restrict__ x_mod, const short* __restrict__ Wf,
    const int* __restrict__ didx, const int* __restrict__ csr,
    const float* __restrict__ att, float* __restrict__ pooled) {
    __shared__ float Yl[VB * 132];                // 33 KB, row stride 132
    __shared__ float attl[VB];
    __shared__ int didxl[VB];
    int tid = threadIdx.x;
    int vbase = blockIdx.x * VB;
    if (tid < VB) {
        int v = vbase + tid;
        if (v < V_VIEWS) {
            didxl[tid] = didx[v];
            attl[tid] = att[v];
        } else {
            didxl[tid] = didx[V_VIEWS - 1];
            attl[tid] = 0.f;
        }
    }
    __syncthreads();

    int w = tid >> 6, lane = tid & 63;
    int row16 = lane & 15;
    int kq = lane >> 4;
    int k0 = kq << 3;
    f32x4 acc[8];
    for (int j = 0; j < 8; ++j) acc[j] = (f32x4){0.f, 0.f, 0.f, 0.f};

    int v = vbase + w * 16 + row16;
    if (v >= V_VIEWS) v = V_VIEWS - 1;            // att=0 handles padding
    const float* xp = x_mod + (size_t)v * IN_MOD;

#pragma unroll
    for (int kk = 0; kk < 4; ++kk) {
        float4 x0 = *(const float4*)(xp + kk * 32 + k0);
        float4 x1 = *(const float4*)(xp + kk * 32 + k0 + 4);
        bf16x8 a;
        a[0] = f2bf(x0.x); a[1] = f2bf(x0.y); a[2] = f2bf(x0.z); a[3] = f2bf(x0.w);
        a[4] = f2bf(x1.x); a[5] = f2bf(x1.y); a[6] = f2bf(x1.z); a[7] = f2bf(x1.w);
        const bf16x8* wf = (const bf16x8*)(Wf + ((size_t)(kk * 8) * 64 + lane) * 8);
#pragma unroll
        for (int j = 0; j < 8; ++j) {
            bf16x8 b = wf[j * 64];
            acc[j] = __builtin_amdgcn_mfma_f32_16x16x32_bf16(a, b, acc[j], 0, 0, 0);
        }
    }
    // epilogue: relu, att-scale, stage to LDS  (C/D: col=lane&15, row=(lane>>4)*4+r)
#pragma unroll
    for (int j = 0; j < 8; ++j) {
        int ch = j * 16 + row16;
        int rbase = w * 16 + (kq << 2);
#pragma unroll
        for (int r = 0; r < 4; ++r) {
            int rw = rbase + r;
            Yl[rw * 132 + ch] = fmaxf(acc[j][r], 0.f) * attl[rw];
        }
    }
    __syncthreads();
    // segmented scan over 64 rows, one thread per channel
    if (tid < IN_MOD) {
        int c = tid;
        float s_acc = 0.f;
        int cur = didxl[0];
        for (int r = 0; r < VB; ++r) {
            int s = didxl[r];
            if (s != cur) {
                if (csr[cur] >= vbase && csr[cur + 1] <= vbase + VB)
                    pooled[(size_t)cur * IN_MOD + c] = s_acc;
                else
                    atomicAdd(&pooled[(size_t)cur * IN_MOD + c], s_acc);
                s_acc = 0.f; cur = s;
            }
            s_acc += Yl[r * 132 + c];
        }
        if (csr[cur] >= vbase && csr[cur + 1] <= vbase + VB)
            pooled[(size_t)cur * IN_MOD + c] = s_acc;
        else
            atomicAdd(&pooled[(size_t)cur * IN_MOD + c], s_acc);
    }
}

// ---------------- kD: out = (pooled @ Wmod2) * gate, in place; x_seen ----------------
__global__ __launch_bounds__(256) void kD_final(
    const float* __restrict__ Wmod2,
    const float* __restrict__ segmax, const int* __restrict__ csr,
    const float* __restrict__ g_w, const float* __restrict__ g_b,
    float* __restrict__ out) {
    __shared__ float Wl[IN_MOD * IN_MOD];
    __shared__ float rowl[2][IN_MOD];
    int tid = threadIdx.x;
    for (int i = tid; i < IN_MOD * IN_MOD; i += 256) Wl[i] = Wmod2[i];
    __syncthreads();
    float gw = g_w[0], gb = g_b[0];
    int h = tid >> 7, c = tid & 127;
    for (int s0 = blockIdx.x * 2; s0 < N_PTS; s0 += gridDim.x * 2) {
        int s = s0 + h;
        rowl[h][c] = out[(size_t)s * IN_MOD + c];
        __syncthreads();
        float acc = 0.f;
        for (int k = 0; k < IN_MOD; ++k) acc += rowl[h][k] * Wl[k * IN_MOD + c];
        bool ne = csr[s + 1] > csr[s];
        float gin = ne ? segmax[s] : 0.f;
        float gate = tanhf(fmaxf(gw * gin + gb, 0.f));
        out[(size_t)s * IN_MOD + c] = acc * gate;
        if (c == 0) out[(size_t)N_PTS * IN_MOD + s] = ne ? 1.f : 0.f;
        __syncthreads();
    }
}

extern "C" void kernel_launch(void* const* d_in, const int* in_sizes, int n_in,
                              void* d_out, int out_size, void* d_ws, size_t ws_size,
                              hipStream_t stream) {
    (void)in_sizes; (void)n_in; (void)out_size; (void)ws_size;
    const float* x_main = (const float*)d_in[0];
    const float* x_mod  = (const float*)d_in[1];
    const float* x_map  = (const float*)d_in[2];
    const int*   csr    = (const int*)d_in[3];
    const float* W_main1 = (const float*)d_in[4];
    const float* W_main2 = (const float*)d_in[5];
    const float* W_map1  = (const float*)d_in[6];
    const float* W_map2  = (const float*)d_in[7];
    const float* W_mod1  = (const float*)d_in[8];
    const float* W_mod2  = (const float*)d_in[9];
    const float* WQ = (const float*)d_in[10];
    const float* bQ = (const float*)d_in[11];
    const float* WK = (const float*)d_in[12];
    const float* bK = (const float*)d_in[13];
    const float* g_w = (const float*)d_in[14];
    const float* g_b = (const float*)d_in[15];
    float* out = (float*)d_out;

    char* ws = (char*)d_ws;
    int*   didx   = (int*)ws;                       // [ 0.0,  2.0 MB)
    float* wq     = (float*)(ws + 2000000);         // [ 2.0,  8.4 MB)
    float* qb     = (float*)(ws + 8400000);         // [ 8.4,  8.6 MB)
    float* ctxW2b = (float*)(ws + 8600000);         // [ 8.6, 15.0 MB)
    float* comp   = (float*)(ws + 15000000);        // [15.0, 17.0 MB)  comp -> att
    float* segmax = (float*)(ws + 17000000);        // [17.0, 17.2 MB)
    short* Wf     = (short*)(ws + 17200000);        // [17.2, 17.24 MB) 32 KB
    float* pooled = out;

    k0_setup<<<512, 256, 0, stream>>>(csr, W_mod1, didx, pooled, Wf);
    kA_main_q<<<(N_PTS + 7) / 8, 256, 0, stream>>>(x_main, W_main1, W_main2, WQ, bQ,
                                                   WK, bK, wq, qb);
    kB2_ctx<<<(N_PTS + 3) / 4, 256, 0, stream>>>(x_map, csr, W_map1, W_map2, ctxW2b);
    kB3_comp<<<(V_VIEWS + 63) / 64, 256, 0, stream>>>(x_map, didx, W_map1, W_map2,
                                                      ctxW2b, wq, qb, comp);
    kB4_att<<<(N_PTS + 3) / 4, 256, 0, stream>>>(comp, csr, segmax);
    kC_pool<<<(V_VIEWS + VB - 1) / VB, 256, 0, stream>>>(x_mod, Wf, didx, csr,
                                                         comp, pooled);
    kD_final<<<2048, 256, 0, stream>>>(W_mod2, segmax, csr, g_w, g_b, out);
}

// Round 5
// 401.936 us; speedup vs baseline: 2.9780x; 1.4119x over previous
//
#include <hip/hip_runtime.h>
#include <math.h>

#define N_PTS 50000
#define V_VIEWS 500000
#define IN_MAIN 64
#define IN_MAP 16
#define IN_MOD 128
#define NC 32
#define NC_QK 8
#define SEG_EPS 1e-12f

typedef short bf16x8 __attribute__((ext_vector_type(8)));
typedef float f32x4 __attribute__((ext_vector_type(4)));

static __device__ __forceinline__ short f2bf(float x) {
    union { float f; unsigned u; } v; v.f = x;
    unsigned r = v.u + 0x7fffu + ((v.u >> 16) & 1u);   // RNE
    return (short)(r >> 16);
}

// ws layout (bytes):
//   didx    [ 0.0, 2.0 MB)  V int
//   wq      [ 2.0, 8.4 MB)  N*32 f32
//   qb      [ 8.4, 8.6 MB)  N f32
//   ctxW2b  [ 8.6,15.0 MB)  N*32 f32
//   comp    [15.0,17.0 MB)  V f32 (-> att in place)
//   segmax  [17.0,17.2 MB)  N f32
//   Wf      [17.20,17.233 MB) 16384 bf16 — W_mod1 fragment-linear (kC B-frags)
//   W1f     [17.240,17.242 MB) 1024 bf16 — W_map1 frag-linear (kB3 MFMA1 B, k>=16 zero)
//   W2af    [17.244,17.246 MB) 1024 bf16 — W_map2 rows 0..31 frag-linear (kB3 MFMA2 B)
// pooled accumulator = d_out's x_pool region, finalized in place by kD.

// ---------------- k0: didx fill + pooled zero + Wf/W1f/W2af build ----------------
__global__ __launch_bounds__(256) void k0_setup(const int* __restrict__ csr,
                                                const float* __restrict__ Wmod1,
                                                const float* __restrict__ Wm1,
                                                const float* __restrict__ Wm2,
                                                int* __restrict__ didx,
                                                float* __restrict__ pooled,
                                                short* __restrict__ Wf,
                                                short* __restrict__ W1f,
                                                short* __restrict__ W2af) {
    int t = blockIdx.x * blockDim.x + threadIdx.x;
    int total = gridDim.x * blockDim.x;
    if (t < N_PTS) {
        int a = csr[t], b = csr[t + 1];
        for (int v = a; v < b; ++v) didx[v] = t;
    }
    for (int i = t; i < N_PTS * IN_MOD; i += total) pooled[i] = 0.f;
    for (int i = t; i < IN_MOD * IN_MOD; i += total) {
        int e = i & 7, l = (i >> 3) & 63, j = (i >> 9) & 7, kk = i >> 12;
        int k = kk * 32 + ((l >> 4) << 3) + e;
        int ch = (j << 4) + (l & 15);
        Wf[i] = f2bf(Wmod1[k * IN_MOD + ch]);
    }
    // kB3 B-frags: frag j in 0..1, lane l, elem e: k=(l>>4)*8+e, ch=j*16+(l&15)
    for (int i = t; i < 1024; i += total) {
        int e = i & 7, l = (i >> 3) & 63, j = i >> 9;
        int k = ((l >> 4) << 3) + e;
        int ch = (j << 4) + (l & 15);
        W1f[i] = (k < IN_MAP) ? f2bf(Wm1[k * NC + ch]) : (short)0;
        W2af[i] = f2bf(Wm2[k * NC + ch]);
    }
}

// ---------------- kA: x_main -> h_main -> q -> wq[N,32], qb[N] ----------------
__global__ __launch_bounds__(256) void kA_main_q(
    const float* __restrict__ x_main, const float* __restrict__ W1,
    const float* __restrict__ W2, const float* __restrict__ WQ,
    const float* __restrict__ bQ, const float* __restrict__ WK,
    const float* __restrict__ bK,
    float* __restrict__ wq, float* __restrict__ qb) {
    __shared__ float W1l[IN_MAIN * NC];
    __shared__ float W2l[NC * NC];
    __shared__ float WQl[NC * NC_QK];
    __shared__ float WKl[NC * NC_QK];
    __shared__ float bQl[NC_QK];
    __shared__ float bKl[NC_QK];
    __shared__ float h1buf[8][NC];
    __shared__ float h2buf[8][NC];
    __shared__ float qbuf[8][NC_QK];
    int tid = threadIdx.x;
    for (int i = tid; i < IN_MAIN * NC; i += 256) W1l[i] = W1[i];
    for (int i = tid; i < NC * NC; i += 256) W2l[i] = W2[i];
    for (int i = tid; i < NC * NC_QK; i += 256) WQl[i] = WQ[i];
    for (int i = tid; i < NC * NC_QK; i += 256) WKl[i] = WK[i];
    if (tid < NC_QK) { bQl[tid] = bQ[tid]; bKl[tid] = bK[tid]; }
    __syncthreads();
    int g = tid >> 5, c = tid & 31;
    int p = blockIdx.x * 8 + g;
    float h1 = 0.f;
    if (p < N_PTS) {
        const float* xr = x_main + (size_t)p * IN_MAIN;
        for (int k = 0; k < IN_MAIN; ++k) h1 += xr[k] * W1l[k * NC + c];
        h1 = fmaxf(h1, 0.f);
    }
    h1buf[g][c] = h1;
    __syncthreads();
    float h2 = 0.f;
    for (int j = 0; j < NC; ++j) h2 += h1buf[g][j] * W2l[j * NC + c];
    h2buf[g][c] = h2;
    __syncthreads();
    if (c < NC_QK) {
        float acc = bQl[c];
        for (int j = 0; j < NC; ++j) acc += h2buf[g][j] * WQl[j * NC_QK + c];
        qbuf[g][c] = acc;
    }
    __syncthreads();
    if (p < N_PTS) {
        float w = 0.f;
        for (int j = 0; j < NC_QK; ++j) w += WKl[c * NC_QK + j] * qbuf[g][j];
        wq[(size_t)p * NC + c] = w;
        if (c == 0) {
            float b = 0.f;
            for (int j = 0; j < NC_QK; ++j) b += bKl[j] * qbuf[g][j];
            qb[p] = b;
        }
    }
}

// ---------------- kB2: per-segment ctx = segmax(relu(x_map@W1)); ctxW2b = ctx @ W2b ----------------
__global__ __launch_bounds__(256) void kB2_ctx(
    const float* __restrict__ x_map, const int* __restrict__ csr,
    const float* __restrict__ Wm1, const float* __restrict__ Wm2,
    float* __restrict__ ctxW2b) {
    __shared__ float W1l[IN_MAP * NC];
    __shared__ float W2bl[NC * NC];
    int tid = threadIdx.x;
    for (int i = tid; i < IN_MAP * NC; i += 256) W1l[i] = Wm1[i];
    for (int i = tid; i < NC * NC; i += 256) W2bl[i] = Wm2[NC * NC + i];
    __syncthreads();
    int wid = tid >> 6, lane = tid & 63;
    int seg = blockIdx.x * 4 + wid;
    if (seg >= N_PTS) return;
    int v0 = csr[seg], v1 = csr[seg + 1];
    int half = lane >> 5, c = lane & 31;
    float ctx = 0.f;
    for (int v = v0 + half; v < v1; v += 2) {
        const float4* xr = (const float4*)(x_map + (size_t)v * IN_MAP);
        float4 a = xr[0], b = xr[1], d = xr[2], e = xr[3];
        float h = a.x * W1l[0 * NC + c] + a.y * W1l[1 * NC + c]
                + a.z * W1l[2 * NC + c] + a.w * W1l[3 * NC + c]
                + b.x * W1l[4 * NC + c] + b.y * W1l[5 * NC + c]
                + b.z * W1l[6 * NC + c] + b.w * W1l[7 * NC + c]
                + d.x * W1l[8 * NC + c] + d.y * W1l[9 * NC + c]
                + d.z * W1l[10 * NC + c] + d.w * W1l[11 * NC + c]
                + e.x * W1l[12 * NC + c] + e.y * W1l[13 * NC + c]
                + e.z * W1l[14 * NC + c] + e.w * W1l[15 * NC + c];
        ctx = fmaxf(ctx, h);
    }
    ctx = fmaxf(ctx, __shfl_xor(ctx, 32));
    float val = 0.f;
    for (int j = 0; j < NC; ++j) val += __shfl(ctx, j, 64) * W2bl[j * NC + c];
    if (half == 0) ctxW2b[(size_t)seg * NC + c] = val;
}

// ---------------- kB3: dense comp over views  [bf16 MFMA, 16 views/wave] ----------------
// h = relu(x_map@W1) via MFMA1 (K=32, top 16 k zero); LDS-transpose h (within-wave,
// no barrier); m = relu(h@W2a + ctxW2b[s]) via MFMA2; comp = (m.wq[s] + qb[s])/sqrt(8).
__global__ __launch_bounds__(256) void kB3_comp(
    const float* __restrict__ x_map, const int* __restrict__ didx,
    const short* __restrict__ W1f, const short* __restrict__ W2af,
    const float* __restrict__ ctxW2b, const float* __restrict__ wq,
    const float* __restrict__ qb, float* __restrict__ comp) {
    __shared__ float hl[4][16 * 36];          // per-wave h bounce, stride 36 dwords
    int tid = threadIdx.x;
    int w = tid >> 6, lane = tid & 63;
    int vbase = blockIdx.x * 64 + w * 16;
    if (vbase >= V_VIEWS) return;             // no barriers below: safe early-exit
    const bf16x8* pW1 = (const bf16x8*)W1f;
    const bf16x8* pW2 = (const bf16x8*)W2af;
    bf16x8 b1a = pW1[lane], b1b = pW1[64 + lane];
    bf16x8 b2a = pW2[lane], b2b = pW2[64 + lane];

    // A1 frag: row(view)=lane&15, k=(lane>>4)*8+e  (k>=16 -> zero)
    bf16x8 a1 = (bf16x8){0, 0, 0, 0, 0, 0, 0, 0};
    if (lane < 32) {
        const float* xp = x_map + (size_t)(vbase + (lane & 15)) * IN_MAP + ((lane >> 4) << 3);
        float4 x0 = *(const float4*)xp;
        float4 x1 = *(const float4*)(xp + 4);
        a1[0] = f2bf(x0.x); a1[1] = f2bf(x0.y); a1[2] = f2bf(x0.z); a1[3] = f2bf(x0.w);
        a1[4] = f2bf(x1.x); a1[5] = f2bf(x1.y); a1[6] = f2bf(x1.z); a1[7] = f2bf(x1.w);
    }
    f32x4 d1a = (f32x4){0.f, 0.f, 0.f, 0.f}, d1b = (f32x4){0.f, 0.f, 0.f, 0.f};
    d1a = __builtin_amdgcn_mfma_f32_16x16x32_bf16(a1, b1a, d1a, 0, 0, 0);
    d1b = __builtin_amdgcn_mfma_f32_16x16x32_bf16(a1, b1b, d1b, 0, 0, 0);

    // relu + stage h to LDS (D layout: col(ch)=lane&15, row(view)=(lane>>4)*4+r)
    float* hw = hl[w];
    int c = lane & 15;
    int vr0 = (lane >> 4) << 2;
#pragma unroll
    for (int r = 0; r < 4; ++r) {
        hw[(vr0 + r) * 36 + c] = fmaxf(d1a[r], 0.f);
        hw[(vr0 + r) * 36 + c + 16] = fmaxf(d1b[r], 0.f);
    }
    // A2 frag: row(view)=lane&15, k(ch)=(lane>>4)*8+e — within-wave LDS read-back
    const float* hr = hw + (lane & 15) * 36 + ((lane >> 4) << 3);
    float4 h0 = *(const float4*)hr;
    float4 h1 = *(const float4*)(hr + 4);
    bf16x8 a2;
    a2[0] = f2bf(h0.x); a2[1] = f2bf(h0.y); a2[2] = f2bf(h0.z); a2[3] = f2bf(h0.w);
    a2[4] = f2bf(h1.x); a2[5] = f2bf(h1.y); a2[6] = f2bf(h1.z); a2[7] = f2bf(h1.w);

    f32x4 d2a = (f32x4){0.f, 0.f, 0.f, 0.f}, d2b = (f32x4){0.f, 0.f, 0.f, 0.f};
    d2a = __builtin_amdgcn_mfma_f32_16x16x32_bf16(a2, b2a, d2a, 0, 0, 0);
    d2b = __builtin_amdgcn_mfma_f32_16x16x32_bf16(a2, b2b, d2b, 0, 0, 0);

    // group G=lane>>4 owns views vg..vg+3 (r=0..3); per-lane chs {c, c+16}
    int vg = vbase + vr0;
    int4 ss = *(const int4*)(didx + vg);
    const int* sp = (const int*)&ss;
    float part[4];
#pragma unroll
    for (int r = 0; r < 4; ++r) {
        size_t so = (size_t)sp[r] * NC;
        float m0 = fmaxf(d2a[r] + ctxW2b[so + c], 0.f);
        float m1 = fmaxf(d2b[r] + ctxW2b[so + c + 16], 0.f);
        part[r] = m0 * wq[so + c] + m1 * wq[so + c + 16];
    }
#pragma unroll
    for (int mask = 1; mask < 16; mask <<= 1) {
#pragma unroll
        for (int r = 0; r < 4; ++r) part[r] += __shfl_xor(part[r], mask);
    }
    if (c == 0) {
        const float inv_sqrt = 0.35355339059327373f;
        float4 o;
        o.x = (part[0] + qb[sp[0]]) * inv_sqrt;
        o.y = (part[1] + qb[sp[1]]) * inv_sqrt;
        o.z = (part[2] + qb[sp[2]]) * inv_sqrt;
        o.w = (part[3] + qb[sp[3]]) * inv_sqrt;
        *(float4*)(comp + vg) = o;
    }
}

// ---------------- kB4: per-segment softmax; comp -> att in place; segmax out ----------------
__global__ __launch_bounds__(256) void kB4_att(
    float* __restrict__ comp, const int* __restrict__ csr,
    float* __restrict__ segmax) {
    int wid = threadIdx.x >> 6, lane = threadIdx.x & 63;
    int seg = blockIdx.x * 4 + wid;
    if (seg >= N_PTS) return;
    int v0 = csr[seg], v1 = csr[seg + 1];
    if (v0 >= v1) {
        if (lane == 0) segmax[seg] = 0.f;
        return;
    }
    float mx = -__builtin_inff();
    for (int v = v0 + lane; v < v1; v += 64) mx = fmaxf(mx, comp[v]);
    for (int o = 32; o > 0; o >>= 1) mx = fmaxf(mx, __shfl_xor(mx, o));
    float sm = 0.f;
    for (int v = v0 + lane; v < v1; v += 64) sm += __expf(comp[v] - mx);
    for (int o = 32; o > 0; o >>= 1) sm += __shfl_xor(sm, o);
    float inv = 1.f / (sm + SEG_EPS);
    for (int v = v0 + lane; v < v1; v += 64) comp[v] = __expf(comp[v] - mx) * inv;
    if (lane == 0) segmax[seg] = mx;
}

// ---------------- kC: pooled += segsum(att * relu(x_mod @ Wmod1))  [bf16 MFMA] ----------------
#define VB 64
__global__ __launch_bounds__(256) void kC_pool(
    const float* __restrict__ x_mod, const short* __restrict__ Wf,
    const int* __restrict__ didx, const int* __restrict__ csr,
    const float* __restrict__ att, float* __restrict__ pooled) {
    __shared__ float Yl[VB * 132];                // 33 KB, row stride 132
    __shared__ float attl[VB];
    __shared__ int didxl[VB];
    int tid = threadIdx.x;
    int vbase = blockIdx.x * VB;
    if (tid < VB) {
        int v = vbase + tid;
        if (v < V_VIEWS) {
            didxl[tid] = didx[v];
            attl[tid] = att[v];
        } else {
            didxl[tid] = didx[V_VIEWS - 1];
            attl[tid] = 0.f;
        }
    }
    __syncthreads();

    int w = tid >> 6, lane = tid & 63;
    int row16 = lane & 15;
    int kq = lane >> 4;
    int k0 = kq << 3;
    f32x4 acc[8];
    for (int j = 0; j < 8; ++j) acc[j] = (f32x4){0.f, 0.f, 0.f, 0.f};

    int v = vbase + w * 16 + row16;
    if (v >= V_VIEWS) v = V_VIEWS - 1;            // att=0 handles padding
    const float* xp = x_mod + (size_t)v * IN_MOD;

#pragma unroll
    for (int kk = 0; kk < 4; ++kk) {
        float4 x0 = *(const float4*)(xp + kk * 32 + k0);
        float4 x1 = *(const float4*)(xp + kk * 32 + k0 + 4);
        bf16x8 a;
        a[0] = f2bf(x0.x); a[1] = f2bf(x0.y); a[2] = f2bf(x0.z); a[3] = f2bf(x0.w);
        a[4] = f2bf(x1.x); a[5] = f2bf(x1.y); a[6] = f2bf(x1.z); a[7] = f2bf(x1.w);
        const bf16x8* wf = (const bf16x8*)(Wf + ((size_t)(kk * 8) * 64 + lane) * 8);
#pragma unroll
        for (int j = 0; j < 8; ++j) {
            bf16x8 b = wf[j * 64];
            acc[j] = __builtin_amdgcn_mfma_f32_16x16x32_bf16(a, b, acc[j], 0, 0, 0);
        }
    }
#pragma unroll
    for (int j = 0; j < 8; ++j) {
        int ch = j * 16 + row16;
        int rbase = w * 16 + (kq << 2);
#pragma unroll
        for (int r = 0; r < 4; ++r) {
            int rw = rbase + r;
            Yl[rw * 132 + ch] = fmaxf(acc[j][r], 0.f) * attl[rw];
        }
    }
    __syncthreads();
    if (tid < IN_MOD) {
        int c = tid;
        float s_acc = 0.f;
        int cur = didxl[0];
        for (int r = 0; r < VB; ++r) {
            int s = didxl[r];
            if (s != cur) {
                if (csr[cur] >= vbase && csr[cur + 1] <= vbase + VB)
                    pooled[(size_t)cur * IN_MOD + c] = s_acc;
                else
                    atomicAdd(&pooled[(size_t)cur * IN_MOD + c], s_acc);
                s_acc = 0.f; cur = s;
            }
            s_acc += Yl[r * 132 + c];
        }
        if (csr[cur] >= vbase && csr[cur + 1] <= vbase + VB)
            pooled[(size_t)cur * IN_MOD + c] = s_acc;
        else
            atomicAdd(&pooled[(size_t)cur * IN_MOD + c], s_acc);
    }
}

// ---------------- kD: out = (pooled @ Wmod2) * gate, in place; x_seen ----------------
__global__ __launch_bounds__(256) void kD_final(
    const float* __restrict__ Wmod2,
    const float* __restrict__ segmax, const int* __restrict__ csr,
    const float* __restrict__ g_w, const float* __restrict__ g_b,
    float* __restrict__ out) {
    __shared__ float Wl[IN_MOD * IN_MOD];
    __shared__ float rowl[2][IN_MOD];
    int tid = threadIdx.x;
    for (int i = tid; i < IN_MOD * IN_MOD; i += 256) Wl[i] = Wmod2[i];
    __syncthreads();
    float gw = g_w[0], gb = g_b[0];
    int h = tid >> 7, c = tid & 127;
    for (int s0 = blockIdx.x * 2; s0 < N_PTS; s0 += gridDim.x * 2) {
        int s = s0 + h;
        rowl[h][c] = out[(size_t)s * IN_MOD + c];
        __syncthreads();
        float acc = 0.f;
        for (int k = 0; k < IN_MOD; ++k) acc += rowl[h][k] * Wl[k * IN_MOD + c];
        bool ne = csr[s + 1] > csr[s];
        float gin = ne ? segmax[s] : 0.f;
        float gate = tanhf(fmaxf(gw * gin + gb, 0.f));
        out[(size_t)s * IN_MOD + c] = acc * gate;
        if (c == 0) out[(size_t)N_PTS * IN_MOD + s] = ne ? 1.f : 0.f;
        __syncthreads();
    }
}

extern "C" void kernel_launch(void* const* d_in, const int* in_sizes, int n_in,
                              void* d_out, int out_size, void* d_ws, size_t ws_size,
                              hipStream_t stream) {
    (void)in_sizes; (void)n_in; (void)out_size; (void)ws_size;
    const float* x_main = (const float*)d_in[0];
    const float* x_mod  = (const float*)d_in[1];
    const float* x_map  = (const float*)d_in[2];
    const int*   csr    = (const int*)d_in[3];
    const float* W_main1 = (const float*)d_in[4];
    const float* W_main2 = (const float*)d_in[5];
    const float* W_map1  = (const float*)d_in[6];
    const float* W_map2  = (const float*)d_in[7];
    const float* W_mod1  = (const float*)d_in[8];
    const float* W_mod2  = (const float*)d_in[9];
    const float* WQ = (const float*)d_in[10];
    const float* bQ = (const float*)d_in[11];
    const float* WK = (const float*)d_in[12];
    const float* bK = (const float*)d_in[13];
    const float* g_w = (const float*)d_in[14];
    const float* g_b = (const float*)d_in[15];
    float* out = (float*)d_out;

    char* ws = (char*)d_ws;
    int*   didx   = (int*)ws;                       // [ 0.0,  2.0 MB)
    float* wq     = (float*)(ws + 2000000);         // [ 2.0,  8.4 MB)
    float* qb     = (float*)(ws + 8400000);         // [ 8.4,  8.6 MB)
    float* ctxW2b = (float*)(ws + 8600000);         // [ 8.6, 15.0 MB)
    float* comp   = (float*)(ws + 15000000);        // [15.0, 17.0 MB)  comp -> att
    float* segmax = (float*)(ws + 17000000);        // [17.0, 17.2 MB)
    short* Wf     = (short*)(ws + 17200000);        // 32 KB
    short* W1f    = (short*)(ws + 17240000);        // 2 KB
    short* W2af   = (short*)(ws + 17244000);        // 2 KB
    float* pooled = out;

    k0_setup<<<512, 256, 0, stream>>>(csr, W_mod1, W_map1, W_map2,
                                      didx, pooled, Wf, W1f, W2af);
    kA_main_q<<<(N_PTS + 7) / 8, 256, 0, stream>>>(x_main, W_main1, W_main2, WQ, bQ,
                                                   WK, bK, wq, qb);
    kB2_ctx<<<(N_PTS + 3) / 4, 256, 0, stream>>>(x_map, csr, W_map1, W_map2, ctxW2b);
    kB3_comp<<<(V_VIEWS + 63) / 64, 256, 0, stream>>>(x_map, didx, W1f, W2af,
                                                      ctxW2b, wq, qb, comp);
    kB4_att<<<(N_PTS + 3) / 4, 256, 0, stream>>>(comp, csr, segmax);
    kC_pool<<<(V_VIEWS + VB - 1) / VB, 256, 0, stream>>>(x_mod, Wf, didx, csr,
                                                         comp, pooled);
    kD_final<<<2048, 256, 0, stream>>>(W_mod2, segmax, csr, g_w, g_b, out);
}

// Round 6
// 262.129 us; speedup vs baseline: 4.5664x; 1.5334x over previous
//
#include <hip/hip_runtime.h>
#include <math.h>

#define N_PTS 50000
#define V_VIEWS 500000
#define IN_MAIN 64
#define IN_MAP 16
#define IN_MOD 128
#define NC 32
#define NC_QK 8
#define SEG_EPS 1e-12f

typedef short bf16x8 __attribute__((ext_vector_type(8)));
typedef float f32x4 __attribute__((ext_vector_type(4)));

static __device__ __forceinline__ short f2bf(float x) {
    union { float f; unsigned u; } v; v.f = x;
    unsigned r = v.u + 0x7fffu + ((v.u >> 16) & 1u);   // RNE
    return (short)(r >> 16);
}

// ws layout (bytes):
//   didx    [ 0.0, 2.0 MB)  V int
//   wq      [ 2.0, 8.4 MB)  N*32 f32
//   qb      [ 8.4, 8.6 MB)  N f32
//   ctxW2b  [ 8.6,15.0 MB)  N*32 f32
//   comp    [15.0,17.0 MB)  V f32 (-> att in place)
//   segmax  [17.0,17.2 MB)  N f32
//   Wf      [17200000, +32 KB) W_mod1 fragment-linear bf16 (kC B-frags)
//   W1f     [17240000, + 2 KB) W_map1 frag-linear (kB3 MFMA1 B, k>=16 zero)
//   W2af    [17244000, + 2 KB) W_map2 rows 0..31 frag-linear (kB3 MFMA2 B)
//   W2f     [17248000, +32 KB) W_mod2 fragment-linear bf16 (kD B-frags)
// pooled accumulator = d_out's x_pool region, finalized in place by kD.

// ---------------- k0: didx fill + pooled zero + Wf/W1f/W2af/W2f build ----------------
__global__ __launch_bounds__(256) void k0_setup(const int* __restrict__ csr,
                                                const float* __restrict__ Wmod1,
                                                const float* __restrict__ Wmod2,
                                                const float* __restrict__ Wm1,
                                                const float* __restrict__ Wm2,
                                                int* __restrict__ didx,
                                                float* __restrict__ pooled,
                                                short* __restrict__ Wf,
                                                short* __restrict__ W1f,
                                                short* __restrict__ W2af,
                                                short* __restrict__ W2f) {
    int t = blockIdx.x * blockDim.x + threadIdx.x;
    int total = gridDim.x * blockDim.x;
    if (t < N_PTS) {
        int a = csr[t], b = csr[t + 1];
        for (int v = a; v < b; ++v) didx[v] = t;
    }
    for (int i = t; i < N_PTS * IN_MOD; i += total) pooled[i] = 0.f;
    for (int i = t; i < IN_MOD * IN_MOD; i += total) {
        int e = i & 7, l = (i >> 3) & 63, j = (i >> 9) & 7, kk = i >> 12;
        int k = kk * 32 + ((l >> 4) << 3) + e;
        int ch = (j << 4) + (l & 15);
        Wf[i] = f2bf(Wmod1[k * IN_MOD + ch]);
        W2f[i] = f2bf(Wmod2[k * IN_MOD + ch]);
    }
    // kB3 B-frags: frag j in 0..1, lane l, elem e: k=(l>>4)*8+e, ch=j*16+(l&15)
    for (int i = t; i < 1024; i += total) {
        int e = i & 7, l = (i >> 3) & 63, j = i >> 9;
        int k = ((l >> 4) << 3) + e;
        int ch = (j << 4) + (l & 15);
        W1f[i] = (k < IN_MAP) ? f2bf(Wm1[k * NC + ch]) : (short)0;
        W2af[i] = f2bf(Wm2[k * NC + ch]);
    }
}

// ---------------- kA: x_main -> h_main -> q -> wq[N,32], qb[N] ----------------
__global__ __launch_bounds__(256) void kA_main_q(
    const float* __restrict__ x_main, const float* __restrict__ W1,
    const float* __restrict__ W2, const float* __restrict__ WQ,
    const float* __restrict__ bQ, const float* __restrict__ WK,
    const float* __restrict__ bK,
    float* __restrict__ wq, float* __restrict__ qb) {
    __shared__ float W1l[IN_MAIN * NC];
    __shared__ float W2l[NC * NC];
    __shared__ float WQl[NC * NC_QK];
    __shared__ float WKl[NC * NC_QK];
    __shared__ float bQl[NC_QK];
    __shared__ float bKl[NC_QK];
    __shared__ float h1buf[8][NC];
    __shared__ float h2buf[8][NC];
    __shared__ float qbuf[8][NC_QK];
    int tid = threadIdx.x;
    for (int i = tid; i < IN_MAIN * NC; i += 256) W1l[i] = W1[i];
    for (int i = tid; i < NC * NC; i += 256) W2l[i] = W2[i];
    for (int i = tid; i < NC * NC_QK; i += 256) WQl[i] = WQ[i];
    for (int i = tid; i < NC * NC_QK; i += 256) WKl[i] = WK[i];
    if (tid < NC_QK) { bQl[tid] = bQ[tid]; bKl[tid] = bK[tid]; }
    __syncthreads();
    int g = tid >> 5, c = tid & 31;
    int p = blockIdx.x * 8 + g;
    float h1 = 0.f;
    if (p < N_PTS) {
        const float* xr = x_main + (size_t)p * IN_MAIN;
        for (int k = 0; k < IN_MAIN; ++k) h1 += xr[k] * W1l[k * NC + c];
        h1 = fmaxf(h1, 0.f);
    }
    h1buf[g][c] = h1;
    __syncthreads();
    float h2 = 0.f;
    for (int j = 0; j < NC; ++j) h2 += h1buf[g][j] * W2l[j * NC + c];
    h2buf[g][c] = h2;
    __syncthreads();
    if (c < NC_QK) {
        float acc = bQl[c];
        for (int j = 0; j < NC; ++j) acc += h2buf[g][j] * WQl[j * NC_QK + c];
        qbuf[g][c] = acc;
    }
    __syncthreads();
    if (p < N_PTS) {
        float w = 0.f;
        for (int j = 0; j < NC_QK; ++j) w += WKl[c * NC_QK + j] * qbuf[g][j];
        wq[(size_t)p * NC + c] = w;
        if (c == 0) {
            float b = 0.f;
            for (int j = 0; j < NC_QK; ++j) b += bKl[j] * qbuf[g][j];
            qb[p] = b;
        }
    }
}

// ---------------- kB2: per-segment ctx = segmax(relu(x_map@W1)); ctxW2b = ctx @ W2b ----------------
__global__ __launch_bounds__(256) void kB2_ctx(
    const float* __restrict__ x_map, const int* __restrict__ csr,
    const float* __restrict__ Wm1, const float* __restrict__ Wm2,
    float* __restrict__ ctxW2b) {
    __shared__ float W1l[IN_MAP * NC];
    __shared__ float W2bl[NC * NC];
    int tid = threadIdx.x;
    for (int i = tid; i < IN_MAP * NC; i += 256) W1l[i] = Wm1[i];
    for (int i = tid; i < NC * NC; i += 256) W2bl[i] = Wm2[NC * NC + i];
    __syncthreads();
    int wid = tid >> 6, lane = tid & 63;
    int seg = blockIdx.x * 4 + wid;
    if (seg >= N_PTS) return;
    int v0 = csr[seg], v1 = csr[seg + 1];
    int half = lane >> 5, c = lane & 31;
    float ctx = 0.f;
    for (int v = v0 + half; v < v1; v += 2) {
        const float4* xr = (const float4*)(x_map + (size_t)v * IN_MAP);
        float4 a = xr[0], b = xr[1], d = xr[2], e = xr[3];
        float h = a.x * W1l[0 * NC + c] + a.y * W1l[1 * NC + c]
                + a.z * W1l[2 * NC + c] + a.w * W1l[3 * NC + c]
                + b.x * W1l[4 * NC + c] + b.y * W1l[5 * NC + c]
                + b.z * W1l[6 * NC + c] + b.w * W1l[7 * NC + c]
                + d.x * W1l[8 * NC + c] + d.y * W1l[9 * NC + c]
                + d.z * W1l[10 * NC + c] + d.w * W1l[11 * NC + c]
                + e.x * W1l[12 * NC + c] + e.y * W1l[13 * NC + c]
                + e.z * W1l[14 * NC + c] + e.w * W1l[15 * NC + c];
        ctx = fmaxf(ctx, h);
    }
    ctx = fmaxf(ctx, __shfl_xor(ctx, 32));
    float val = 0.f;
    for (int j = 0; j < NC; ++j) val += __shfl(ctx, j, 64) * W2bl[j * NC + c];
    if (half == 0) ctxW2b[(size_t)seg * NC + c] = val;
}

// ---------------- kB3: dense comp over views  [bf16 MFMA, 16 views/wave] ----------------
__global__ __launch_bounds__(256) void kB3_comp(
    const float* __restrict__ x_map, const int* __restrict__ didx,
    const short* __restrict__ W1f, const short* __restrict__ W2af,
    const float* __restrict__ ctxW2b, const float* __restrict__ wq,
    const float* __restrict__ qb, float* __restrict__ comp) {
    __shared__ float hl[4][16 * 36];          // per-wave h bounce, stride 36 dwords
    int tid = threadIdx.x;
    int w = tid >> 6, lane = tid & 63;
    int vbase = blockIdx.x * 64 + w * 16;
    if (vbase >= V_VIEWS) return;             // no barriers below: safe early-exit
    const bf16x8* pW1 = (const bf16x8*)W1f;
    const bf16x8* pW2 = (const bf16x8*)W2af;
    bf16x8 b1a = pW1[lane], b1b = pW1[64 + lane];
    bf16x8 b2a = pW2[lane], b2b = pW2[64 + lane];

    bf16x8 a1 = (bf16x8){0, 0, 0, 0, 0, 0, 0, 0};
    if (lane < 32) {
        const float* xp = x_map + (size_t)(vbase + (lane & 15)) * IN_MAP + ((lane >> 4) << 3);
        float4 x0 = *(const float4*)xp;
        float4 x1 = *(const float4*)(xp + 4);
        a1[0] = f2bf(x0.x); a1[1] = f2bf(x0.y); a1[2] = f2bf(x0.z); a1[3] = f2bf(x0.w);
        a1[4] = f2bf(x1.x); a1[5] = f2bf(x1.y); a1[6] = f2bf(x1.z); a1[7] = f2bf(x1.w);
    }
    f32x4 d1a = (f32x4){0.f, 0.f, 0.f, 0.f}, d1b = (f32x4){0.f, 0.f, 0.f, 0.f};
    d1a = __builtin_amdgcn_mfma_f32_16x16x32_bf16(a1, b1a, d1a, 0, 0, 0);
    d1b = __builtin_amdgcn_mfma_f32_16x16x32_bf16(a1, b1b, d1b, 0, 0, 0);

    float* hw = hl[w];
    int c = lane & 15;
    int vr0 = (lane >> 4) << 2;
#pragma unroll
    for (int r = 0; r < 4; ++r) {
        hw[(vr0 + r) * 36 + c] = fmaxf(d1a[r], 0.f);
        hw[(vr0 + r) * 36 + c + 16] = fmaxf(d1b[r], 0.f);
    }
    const float* hr = hw + (lane & 15) * 36 + ((lane >> 4) << 3);
    float4 h0 = *(const float4*)hr;
    float4 h1 = *(const float4*)(hr + 4);
    bf16x8 a2;
    a2[0] = f2bf(h0.x); a2[1] = f2bf(h0.y); a2[2] = f2bf(h0.z); a2[3] = f2bf(h0.w);
    a2[4] = f2bf(h1.x); a2[5] = f2bf(h1.y); a2[6] = f2bf(h1.z); a2[7] = f2bf(h1.w);

    f32x4 d2a = (f32x4){0.f, 0.f, 0.f, 0.f}, d2b = (f32x4){0.f, 0.f, 0.f, 0.f};
    d2a = __builtin_amdgcn_mfma_f32_16x16x32_bf16(a2, b2a, d2a, 0, 0, 0);
    d2b = __builtin_amdgcn_mfma_f32_16x16x32_bf16(a2, b2b, d2b, 0, 0, 0);

    int vg = vbase + vr0;
    int4 ss = *(const int4*)(didx + vg);
    const int* sp = (const int*)&ss;
    float part[4];
#pragma unroll
    for (int r = 0; r < 4; ++r) {
        size_t so = (size_t)sp[r] * NC;
        float m0 = fmaxf(d2a[r] + ctxW2b[so + c], 0.f);
        float m1 = fmaxf(d2b[r] + ctxW2b[so + c + 16], 0.f);
        part[r] = m0 * wq[so + c] + m1 * wq[so + c + 16];
    }
#pragma unroll
    for (int mask = 1; mask < 16; mask <<= 1) {
#pragma unroll
        for (int r = 0; r < 4; ++r) part[r] += __shfl_xor(part[r], mask);
    }
    if (c == 0) {
        const float inv_sqrt = 0.35355339059327373f;
        float4 o;
        o.x = (part[0] + qb[sp[0]]) * inv_sqrt;
        o.y = (part[1] + qb[sp[1]]) * inv_sqrt;
        o.z = (part[2] + qb[sp[2]]) * inv_sqrt;
        o.w = (part[3] + qb[sp[3]]) * inv_sqrt;
        *(float4*)(comp + vg) = o;
    }
}

// ---------------- kB4: per-segment softmax; comp -> att in place; segmax out ----------------
__global__ __launch_bounds__(256) void kB4_att(
    float* __restrict__ comp, const int* __restrict__ csr,
    float* __restrict__ segmax) {
    int wid = threadIdx.x >> 6, lane = threadIdx.x & 63;
    int seg = blockIdx.x * 4 + wid;
    if (seg >= N_PTS) return;
    int v0 = csr[seg], v1 = csr[seg + 1];
    if (v0 >= v1) {
        if (lane == 0) segmax[seg] = 0.f;
        return;
    }
    float mx = -__builtin_inff();
    for (int v = v0 + lane; v < v1; v += 64) mx = fmaxf(mx, comp[v]);
    for (int o = 32; o > 0; o >>= 1) mx = fmaxf(mx, __shfl_xor(mx, o));
    float sm = 0.f;
    for (int v = v0 + lane; v < v1; v += 64) sm += __expf(comp[v] - mx);
    for (int o = 32; o > 0; o >>= 1) sm += __shfl_xor(sm, o);
    float inv = 1.f / (sm + SEG_EPS);
    for (int v = v0 + lane; v < v1; v += 64) comp[v] = __expf(comp[v] - mx) * inv;
    if (lane == 0) segmax[seg] = mx;
}

// ---------------- kC: pooled += segsum(att * relu(x_mod @ Wmod1))  [bf16 MFMA] ----------------
#define VB 64
__global__ __launch_bounds__(256) void kC_pool(
    const float* __restrict__ x_mod, const short* __restrict__ Wf,
    const int* __restrict__ didx, const int* __restrict__ csr,
    const float* __restrict__ att, float* __restrict__ pooled) {
    __shared__ float Yl[VB * 132];                // 33 KB, row stride 132
    __shared__ float attl[VB];
    __shared__ int didxl[VB];
    int tid = threadIdx.x;
    int vbase = blockIdx.x * VB;
    if (tid < VB) {
        int v = vbase + tid;
        if (v < V_VIEWS) {
            didxl[tid] = didx[v];
            attl[tid] = att[v];
        } else {
            didxl[tid] = didx[V_VIEWS - 1];
            attl[tid] = 0.f;
        }
    }
    __syncthreads();

    int w = tid >> 6, lane = tid & 63;
    int row16 = lane & 15;
    int kq = lane >> 4;
    int k0 = kq << 3;
    f32x4 acc[8];
    for (int j = 0; j < 8; ++j) acc[j] = (f32x4){0.f, 0.f, 0.f, 0.f};

    int v = vbase + w * 16 + row16;
    if (v >= V_VIEWS) v = V_VIEWS - 1;            // att=0 handles padding
    const float* xp = x_mod + (size_t)v * IN_MOD;

#pragma unroll
    for (int kk = 0; kk < 4; ++kk) {
        float4 x0 = *(const float4*)(xp + kk * 32 + k0);
        float4 x1 = *(const float4*)(xp + kk * 32 + k0 + 4);
        bf16x8 a;
        a[0] = f2bf(x0.x); a[1] = f2bf(x0.y); a[2] = f2bf(x0.z); a[3] = f2bf(x0.w);
        a[4] = f2bf(x1.x); a[5] = f2bf(x1.y); a[6] = f2bf(x1.z); a[7] = f2bf(x1.w);
        const bf16x8* wf = (const bf16x8*)(Wf + ((size_t)(kk * 8) * 64 + lane) * 8);
#pragma unroll
        for (int j = 0; j < 8; ++j) {
            bf16x8 b = wf[j * 64];
            acc[j] = __builtin_amdgcn_mfma_f32_16x16x32_bf16(a, b, acc[j], 0, 0, 0);
        }
    }
#pragma unroll
    for (int j = 0; j < 8; ++j) {
        int ch = j * 16 + row16;
        int rbase = w * 16 + (kq << 2);
#pragma unroll
        for (int r = 0; r < 4; ++r) {
            int rw = rbase + r;
            Yl[rw * 132 + ch] = fmaxf(acc[j][r], 0.f) * attl[rw];
        }
    }
    __syncthreads();
    if (tid < IN_MOD) {
        int c = tid;
        float s_acc = 0.f;
        int cur = didxl[0];
        for (int r = 0; r < VB; ++r) {
            int s = didxl[r];
            if (s != cur) {
                if (csr[cur] >= vbase && csr[cur + 1] <= vbase + VB)
                    pooled[(size_t)cur * IN_MOD + c] = s_acc;
                else
                    atomicAdd(&pooled[(size_t)cur * IN_MOD + c], s_acc);
                s_acc = 0.f; cur = s;
            }
            s_acc += Yl[r * 132 + c];
        }
        if (csr[cur] >= vbase && csr[cur + 1] <= vbase + VB)
            pooled[(size_t)cur * IN_MOD + c] = s_acc;
        else
            atomicAdd(&pooled[(size_t)cur * IN_MOD + c], s_acc);
    }
}

// ---------------- kD: out = (pooled @ Wmod2) * gate, in place [bf16 MFMA]; x_seen ----------------
// 64 rows/block, 4 waves x 16 rows. A-frags read from pooled rows (in d_out),
// B-frags from fragment-linear W2f (L2). In-place safe: each wave reads only its
// own 16 rows, and wave-lockstep program order drains all loads (vmcnt before
// first MFMA use) before any store issues.
__global__ __launch_bounds__(256) void kD_final(
    const short* __restrict__ W2f,
    const float* __restrict__ segmax, const int* __restrict__ csr,
    const float* __restrict__ g_w, const float* __restrict__ g_b,
    float* __restrict__ out) {
    int tid = threadIdx.x;
    int w = tid >> 6, lane = tid & 63;
    int row16 = lane & 15;
    int kq = lane >> 4;
    int k0 = kq << 3;
    int rbase = blockIdx.x * 64 + w * 16;
    float gw = g_w[0], gb = g_b[0];

    int rr = rbase + row16;
    if (rr >= N_PTS) rr = N_PTS - 1;              // clamped read; writes masked below
    const float* xp = out + (size_t)rr * IN_MOD;

    f32x4 acc[8];
    for (int j = 0; j < 8; ++j) acc[j] = (f32x4){0.f, 0.f, 0.f, 0.f};
#pragma unroll
    for (int kk = 0; kk < 4; ++kk) {
        float4 x0 = *(const float4*)(xp + kk * 32 + k0);
        float4 x1 = *(const float4*)(xp + kk * 32 + k0 + 4);
        bf16x8 a;
        a[0] = f2bf(x0.x); a[1] = f2bf(x0.y); a[2] = f2bf(x0.z); a[3] = f2bf(x0.w);
        a[4] = f2bf(x1.x); a[5] = f2bf(x1.y); a[6] = f2bf(x1.z); a[7] = f2bf(x1.w);
        const bf16x8* wf = (const bf16x8*)(W2f + ((size_t)(kk * 8) * 64 + lane) * 8);
#pragma unroll
        for (int j = 0; j < 8; ++j) {
            bf16x8 b = wf[j * 64];
            acc[j] = __builtin_amdgcn_mfma_f32_16x16x32_bf16(a, b, acc[j], 0, 0, 0);
        }
    }
    // rows this lane writes: ro = rbase + kq*4 + r  (C/D: col=lane&15, row=kq*4+r)
    float gate[4];
    int rowv[4];
#pragma unroll
    for (int r = 0; r < 4; ++r) {
        int ro = rbase + (kq << 2) + r;
        rowv[r] = ro;
        if (ro < N_PTS) {
            bool nz = csr[ro + 1] > csr[ro];
            float gin = nz ? segmax[ro] : 0.f;
            gate[r] = tanhf(fmaxf(gw * gin + gb, 0.f));
            if (row16 == 0) out[(size_t)N_PTS * IN_MOD + ro] = nz ? 1.f : 0.f;
        } else {
            gate[r] = 0.f;
        }
    }
#pragma unroll
    for (int j = 0; j < 8; ++j) {
        int ch = j * 16 + row16;
#pragma unroll
        for (int r = 0; r < 4; ++r) {
            if (rowv[r] < N_PTS)
                out[(size_t)rowv[r] * IN_MOD + ch] = acc[j][r] * gate[r];
        }
    }
}

extern "C" void kernel_launch(void* const* d_in, const int* in_sizes, int n_in,
                              void* d_out, int out_size, void* d_ws, size_t ws_size,
                              hipStream_t stream) {
    (void)in_sizes; (void)n_in; (void)out_size; (void)ws_size;
    const float* x_main = (const float*)d_in[0];
    const float* x_mod  = (const float*)d_in[1];
    const float* x_map  = (const float*)d_in[2];
    const int*   csr    = (const int*)d_in[3];
    const float* W_main1 = (const float*)d_in[4];
    const float* W_main2 = (const float*)d_in[5];
    const float* W_map1  = (const float*)d_in[6];
    const float* W_map2  = (const float*)d_in[7];
    const float* W_mod1  = (const float*)d_in[8];
    const float* W_mod2  = (const float*)d_in[9];
    const float* WQ = (const float*)d_in[10];
    const float* bQ = (const float*)d_in[11];
    const float* WK = (const float*)d_in[12];
    const float* bK = (const float*)d_in[13];
    const float* g_w = (const float*)d_in[14];
    const float* g_b = (const float*)d_in[15];
    float* out = (float*)d_out;

    char* ws = (char*)d_ws;
    int*   didx   = (int*)ws;                       // [ 0.0,  2.0 MB)
    float* wq     = (float*)(ws + 2000000);         // [ 2.0,  8.4 MB)
    float* qb     = (float*)(ws + 8400000);         // [ 8.4,  8.6 MB)
    float* ctxW2b = (float*)(ws + 8600000);         // [ 8.6, 15.0 MB)
    float* comp   = (float*)(ws + 15000000);        // [15.0, 17.0 MB)  comp -> att
    float* segmax = (float*)(ws + 17000000);        // [17.0, 17.2 MB)
    short* Wf     = (short*)(ws + 17200000);        // 32 KB
    short* W1f    = (short*)(ws + 17240000);        // 2 KB
    short* W2af   = (short*)(ws + 17244000);        // 2 KB
    short* W2f    = (short*)(ws + 17248000);        // 32 KB
    float* pooled = out;

    k0_setup<<<512, 256, 0, stream>>>(csr, W_mod1, W_mod2, W_map1, W_map2,
                                      didx, pooled, Wf, W1f, W2af, W2f);
    kA_main_q<<<(N_PTS + 7) / 8, 256, 0, stream>>>(x_main, W_main1, W_main2, WQ, bQ,
                                                   WK, bK, wq, qb);
    kB2_ctx<<<(N_PTS + 3) / 4, 256, 0, stream>>>(x_map, csr, W_map1, W_map2, ctxW2b);
    kB3_comp<<<(V_VIEWS + 63) / 64, 256, 0, stream>>>(x_map, didx, W1f, W2af,
                                                      ctxW2b, wq, qb, comp);
    kB4_att<<<(N_PTS + 3) / 4, 256, 0, stream>>>(comp, csr, segmax);
    kC_pool<<<(V_VIEWS + VB - 1) / VB, 256, 0, stream>>>(x_mod, Wf, didx, csr,
                                                         comp, pooled);
    kD_final<<<(N_PTS + 63) / 64, 256, 0, stream>>>(W2f, segmax, csr, g_w, g_b, out);
}

// Round 7
// 235.018 us; speedup vs baseline: 5.0931x; 1.1154x over previous
//
#include <hip/hip_runtime.h>
#include <math.h>

#define N_PTS 50000
#define V_VIEWS 500000
#define IN_MAIN 64
#define IN_MAP 16
#define IN_MOD 128
#define NC 32
#define NC_QK 8
#define SEG_EPS 1e-12f

typedef short bf16x8 __attribute__((ext_vector_type(8)));
typedef float f32x4 __attribute__((ext_vector_type(4)));

static __device__ __forceinline__ short f2bf(float x) {
    union { float f; unsigned u; } v; v.f = x;
    unsigned r = v.u + 0x7fffu + ((v.u >> 16) & 1u);   // RNE
    return (short)(r >> 16);
}

// ws layout (bytes):
//   didx    [ 0.0, 2.0 MB)  V int
//   wq      [ 2.0, 8.4 MB)  N*32 f32
//   qb      [ 8.4, 8.6 MB)  N f32
//   ctxW2b  [ 8.6,15.0 MB)  N*32 f32  — doubles as ctxbits (atomicMax int bits of
//                                       relu'd h max) until kB2b transforms in place
//   comp    [15.0,17.0 MB)  V f32 (-> att in place)
//   segmax  [17.0,17.2 MB)  N f32
//   Wf      [17200000, +32 KB) W_mod1 fragment-linear bf16 (kC B-frags)
//   W1f     [17240000, + 2 KB) W_map1 frag-linear (MFMA1 B, k>=16 zero)
//   W2af    [17244000, + 2 KB) W_map2 rows 0..31 frag-linear (kB3 MFMA2 B)
//   W2f     [17248000, +32 KB) W_mod2 fragment-linear bf16 (kD B-frags)
// pooled accumulator = d_out's x_pool region, finalized in place by kD.

// ---------------- k0: didx fill + pooled zero + ctxbits zero + W frag builds ----------------
__global__ __launch_bounds__(256) void k0_setup(const int* __restrict__ csr,
                                                const float* __restrict__ Wmod1,
                                                const float* __restrict__ Wmod2,
                                                const float* __restrict__ Wm1,
                                                const float* __restrict__ Wm2,
                                                int* __restrict__ didx,
                                                float* __restrict__ pooled,
                                                float* __restrict__ ctxw,
                                                short* __restrict__ Wf,
                                                short* __restrict__ W1f,
                                                short* __restrict__ W2af,
                                                short* __restrict__ W2f) {
    int t = blockIdx.x * blockDim.x + threadIdx.x;
    int total = gridDim.x * blockDim.x;
    if (t < N_PTS) {
        int a = csr[t], b = csr[t + 1];
        for (int v = a; v < b; ++v) didx[v] = t;
    }
    for (int i = t; i < N_PTS * IN_MOD; i += total) pooled[i] = 0.f;
    for (int i = t; i < N_PTS * NC; i += total) ctxw[i] = 0.f;   // ctxbits init (0.0f)
    for (int i = t; i < IN_MOD * IN_MOD; i += total) {
        int e = i & 7, l = (i >> 3) & 63, j = (i >> 9) & 7, kk = i >> 12;
        int k = kk * 32 + ((l >> 4) << 3) + e;
        int ch = (j << 4) + (l & 15);
        Wf[i] = f2bf(Wmod1[k * IN_MOD + ch]);
        W2f[i] = f2bf(Wmod2[k * IN_MOD + ch]);
    }
    // MFMA B-frags for the 32-ch GEMMs: frag j in 0..1, lane l, elem e
    for (int i = t; i < 1024; i += total) {
        int e = i & 7, l = (i >> 3) & 63, j = i >> 9;
        int k = ((l >> 4) << 3) + e;
        int ch = (j << 4) + (l & 15);
        W1f[i] = (k < IN_MAP) ? f2bf(Wm1[k * NC + ch]) : (short)0;
        W2af[i] = f2bf(Wm2[k * NC + ch]);
    }
}

// ---------------- kA: x_main -> h_main -> q -> wq[N,32], qb[N] ----------------
__global__ __launch_bounds__(256) void kA_main_q(
    const float* __restrict__ x_main, const float* __restrict__ W1,
    const float* __restrict__ W2, const float* __restrict__ WQ,
    const float* __restrict__ bQ, const float* __restrict__ WK,
    const float* __restrict__ bK,
    float* __restrict__ wq, float* __restrict__ qb) {
    __shared__ float W1l[IN_MAIN * NC];
    __shared__ float W2l[NC * NC];
    __shared__ float WQl[NC * NC_QK];
    __shared__ float WKl[NC * NC_QK];
    __shared__ float bQl[NC_QK];
    __shared__ float bKl[NC_QK];
    __shared__ float h1buf[8][NC];
    __shared__ float h2buf[8][NC];
    __shared__ float qbuf[8][NC_QK];
    int tid = threadIdx.x;
    for (int i = tid; i < IN_MAIN * NC; i += 256) W1l[i] = W1[i];
    for (int i = tid; i < NC * NC; i += 256) W2l[i] = W2[i];
    for (int i = tid; i < NC * NC_QK; i += 256) WQl[i] = WQ[i];
    for (int i = tid; i < NC * NC_QK; i += 256) WKl[i] = WK[i];
    if (tid < NC_QK) { bQl[tid] = bQ[tid]; bKl[tid] = bK[tid]; }
    __syncthreads();
    int g = tid >> 5, c = tid & 31;
    int p = blockIdx.x * 8 + g;
    float h1 = 0.f;
    if (p < N_PTS) {
        const float* xr = x_main + (size_t)p * IN_MAIN;
        for (int k = 0; k < IN_MAIN; ++k) h1 += xr[k] * W1l[k * NC + c];
        h1 = fmaxf(h1, 0.f);
    }
    h1buf[g][c] = h1;
    __syncthreads();
    float h2 = 0.f;
    for (int j = 0; j < NC; ++j) h2 += h1buf[g][j] * W2l[j * NC + c];
    h2buf[g][c] = h2;
    __syncthreads();
    if (c < NC_QK) {
        float acc = bQl[c];
        for (int j = 0; j < NC; ++j) acc += h2buf[g][j] * WQl[j * NC_QK + c];
        qbuf[g][c] = acc;
    }
    __syncthreads();
    if (p < N_PTS) {
        float w = 0.f;
        for (int j = 0; j < NC_QK; ++j) w += WKl[c * NC_QK + j] * qbuf[g][j];
        wq[(size_t)p * NC + c] = w;
        if (c == 0) {
            float b = 0.f;
            for (int j = 0; j < NC_QK; ++j) b += bKl[j] * qbuf[g][j];
            qb[p] = b;
        }
    }
}

// ---------------- kH: dense ctx = segmax(relu(x_map@W1)) via MFMA + atomicMax ----------------
// 16 views/wave. D layout: lane (kq=lane>>4, c=lane&15) holds views vbase+kq*4+r
// (r=0..3) for chs {c, c+16}. didx is sorted, so runs are contiguous: per-lane
// running max, emit one atomicMax per run end. relu >= 0 => int-bits monotone.
__global__ __launch_bounds__(256) void kH_ctx(
    const float* __restrict__ x_map, const int* __restrict__ didx,
    const short* __restrict__ W1f, int* __restrict__ ctxbits) {
    int tid = threadIdx.x;
    int w = tid >> 6, lane = tid & 63;
    int vbase = blockIdx.x * 64 + w * 16;
    if (vbase >= V_VIEWS) return;
    const bf16x8* pW1 = (const bf16x8*)W1f;
    bf16x8 b1a = pW1[lane], b1b = pW1[64 + lane];

    bf16x8 a1 = (bf16x8){0, 0, 0, 0, 0, 0, 0, 0};
    if (lane < 32) {
        const float* xp = x_map + (size_t)(vbase + (lane & 15)) * IN_MAP + ((lane >> 4) << 3);
        float4 x0 = *(const float4*)xp;
        float4 x1 = *(const float4*)(xp + 4);
        a1[0] = f2bf(x0.x); a1[1] = f2bf(x0.y); a1[2] = f2bf(x0.z); a1[3] = f2bf(x0.w);
        a1[4] = f2bf(x1.x); a1[5] = f2bf(x1.y); a1[6] = f2bf(x1.z); a1[7] = f2bf(x1.w);
    }
    f32x4 d1a = (f32x4){0.f, 0.f, 0.f, 0.f}, d1b = (f32x4){0.f, 0.f, 0.f, 0.f};
    d1a = __builtin_amdgcn_mfma_f32_16x16x32_bf16(a1, b1a, d1a, 0, 0, 0);
    d1b = __builtin_amdgcn_mfma_f32_16x16x32_bf16(a1, b1b, d1b, 0, 0, 0);

    int c = lane & 15, kq = lane >> 4;
    int vg = vbase + (kq << 2);
    int4 ss = *(const int4*)(didx + vg);
    const int* sp = (const int*)&ss;
    float ma = 0.f, mb = 0.f;
#pragma unroll
    for (int r = 0; r < 4; ++r) {
        ma = fmaxf(ma, fmaxf(d1a[r], 0.f));
        mb = fmaxf(mb, fmaxf(d1b[r], 0.f));
        bool runend = (r == 3) || (sp[r + 1] != sp[r]);
        if (runend) {
            atomicMax(&ctxbits[sp[r] * NC + c], __float_as_int(ma));
            atomicMax(&ctxbits[sp[r] * NC + c + 16], __float_as_int(mb));
            ma = 0.f; mb = 0.f;
        }
    }
}

// ---------------- kB2b: ctxW2b = ctx @ W2b, in place (row-local) ----------------
__global__ __launch_bounds__(256) void kB2b_ctxw(
    const float* __restrict__ Wm2, float* __restrict__ ctxw) {
    __shared__ float W2bl[NC * NC];
    __shared__ float ctxl[8][NC];
    int tid = threadIdx.x;
    for (int i = tid; i < NC * NC; i += 256) W2bl[i] = Wm2[NC * NC + i];
    int g = tid >> 5, c = tid & 31;
    int s = blockIdx.x * 8 + g;
    float cv = (s < N_PTS) ? ctxw[(size_t)s * NC + c] : 0.f;
    ctxl[g][c] = cv;
    __syncthreads();
    if (s < N_PTS) {
        float val = 0.f;
        for (int j = 0; j < NC; ++j) val += ctxl[g][j] * W2bl[j * NC + c];
        ctxw[(size_t)s * NC + c] = val;
    }
}

// ---------------- kB3: dense comp over views  [bf16 MFMA, 16 views/wave] ----------------
__global__ __launch_bounds__(256) void kB3_comp(
    const float* __restrict__ x_map, const int* __restrict__ didx,
    const short* __restrict__ W1f, const short* __restrict__ W2af,
    const float* __restrict__ ctxW2b, const float* __restrict__ wq,
    const float* __restrict__ qb, float* __restrict__ comp) {
    __shared__ float hl[4][16 * 36];          // per-wave h bounce, stride 36 dwords
    int tid = threadIdx.x;
    int w = tid >> 6, lane = tid & 63;
    int vbase = blockIdx.x * 64 + w * 16;
    if (vbase >= V_VIEWS) return;             // no barriers below: safe early-exit
    const bf16x8* pW1 = (const bf16x8*)W1f;
    const bf16x8* pW2 = (const bf16x8*)W2af;
    bf16x8 b1a = pW1[lane], b1b = pW1[64 + lane];
    bf16x8 b2a = pW2[lane], b2b = pW2[64 + lane];

    bf16x8 a1 = (bf16x8){0, 0, 0, 0, 0, 0, 0, 0};
    if (lane < 32) {
        const float* xp = x_map + (size_t)(vbase + (lane & 15)) * IN_MAP + ((lane >> 4) << 3);
        float4 x0 = *(const float4*)xp;
        float4 x1 = *(const float4*)(xp + 4);
        a1[0] = f2bf(x0.x); a1[1] = f2bf(x0.y); a1[2] = f2bf(x0.z); a1[3] = f2bf(x0.w);
        a1[4] = f2bf(x1.x); a1[5] = f2bf(x1.y); a1[6] = f2bf(x1.z); a1[7] = f2bf(x1.w);
    }
    f32x4 d1a = (f32x4){0.f, 0.f, 0.f, 0.f}, d1b = (f32x4){0.f, 0.f, 0.f, 0.f};
    d1a = __builtin_amdgcn_mfma_f32_16x16x32_bf16(a1, b1a, d1a, 0, 0, 0);
    d1b = __builtin_amdgcn_mfma_f32_16x16x32_bf16(a1, b1b, d1b, 0, 0, 0);

    float* hw = hl[w];
    int c = lane & 15;
    int vr0 = (lane >> 4) << 2;
#pragma unroll
    for (int r = 0; r < 4; ++r) {
        hw[(vr0 + r) * 36 + c] = fmaxf(d1a[r], 0.f);
        hw[(vr0 + r) * 36 + c + 16] = fmaxf(d1b[r], 0.f);
    }
    const float* hr = hw + (lane & 15) * 36 + ((lane >> 4) << 3);
    float4 h0 = *(const float4*)hr;
    float4 h1 = *(const float4*)(hr + 4);
    bf16x8 a2;
    a2[0] = f2bf(h0.x); a2[1] = f2bf(h0.y); a2[2] = f2bf(h0.z); a2[3] = f2bf(h0.w);
    a2[4] = f2bf(h1.x); a2[5] = f2bf(h1.y); a2[6] = f2bf(h1.z); a2[7] = f2bf(h1.w);

    f32x4 d2a = (f32x4){0.f, 0.f, 0.f, 0.f}, d2b = (f32x4){0.f, 0.f, 0.f, 0.f};
    d2a = __builtin_amdgcn_mfma_f32_16x16x32_bf16(a2, b2a, d2a, 0, 0, 0);
    d2b = __builtin_amdgcn_mfma_f32_16x16x32_bf16(a2, b2b, d2b, 0, 0, 0);

    int vg = vbase + vr0;
    int4 ss = *(const int4*)(didx + vg);
    const int* sp = (const int*)&ss;
    float part[4];
#pragma unroll
    for (int r = 0; r < 4; ++r) {
        size_t so = (size_t)sp[r] * NC;
        float m0 = fmaxf(d2a[r] + ctxW2b[so + c], 0.f);
        float m1 = fmaxf(d2b[r] + ctxW2b[so + c + 16], 0.f);
        part[r] = m0 * wq[so + c] + m1 * wq[so + c + 16];
    }
#pragma unroll
    for (int mask = 1; mask < 16; mask <<= 1) {
#pragma unroll
        for (int r = 0; r < 4; ++r) part[r] += __shfl_xor(part[r], mask);
    }
    if (c == 0) {
        const float inv_sqrt = 0.35355339059327373f;
        float4 o;
        o.x = (part[0] + qb[sp[0]]) * inv_sqrt;
        o.y = (part[1] + qb[sp[1]]) * inv_sqrt;
        o.z = (part[2] + qb[sp[2]]) * inv_sqrt;
        o.w = (part[3] + qb[sp[3]]) * inv_sqrt;
        *(float4*)(comp + vg) = o;
    }
}

// ---------------- kB4: per-segment softmax; comp -> att in place; segmax out ----------------
__global__ __launch_bounds__(256) void kB4_att(
    float* __restrict__ comp, const int* __restrict__ csr,
    float* __restrict__ segmax) {
    int wid = threadIdx.x >> 6, lane = threadIdx.x & 63;
    int seg = blockIdx.x * 4 + wid;
    if (seg >= N_PTS) return;
    int v0 = csr[seg], v1 = csr[seg + 1];
    if (v0 >= v1) {
        if (lane == 0) segmax[seg] = 0.f;
        return;
    }
    float mx = -__builtin_inff();
    for (int v = v0 + lane; v < v1; v += 64) mx = fmaxf(mx, comp[v]);
    for (int o = 32; o > 0; o >>= 1) mx = fmaxf(mx, __shfl_xor(mx, o));
    float sm = 0.f;
    for (int v = v0 + lane; v < v1; v += 64) sm += __expf(comp[v] - mx);
    for (int o = 32; o > 0; o >>= 1) sm += __shfl_xor(sm, o);
    float inv = 1.f / (sm + SEG_EPS);
    for (int v = v0 + lane; v < v1; v += 64) comp[v] = __expf(comp[v] - mx) * inv;
    if (lane == 0) segmax[seg] = mx;
}

// ---------------- kC: pooled += segsum(att * relu(x_mod @ Wmod1))  [bf16 MFMA] ----------------
#define VB 64
__global__ __launch_bounds__(256) void kC_pool(
    const float* __restrict__ x_mod, const short* __restrict__ Wf,
    const int* __restrict__ didx, const int* __restrict__ csr,
    const float* __restrict__ att, float* __restrict__ pooled) {
    __shared__ float Yl[VB * 132];                // 33 KB, row stride 132
    __shared__ float attl[VB];
    __shared__ int didxl[VB];
    int tid = threadIdx.x;
    int vbase = blockIdx.x * VB;
    if (tid < VB) {
        int v = vbase + tid;
        if (v < V_VIEWS) {
            didxl[tid] = didx[v];
            attl[tid] = att[v];
        } else {
            didxl[tid] = didx[V_VIEWS - 1];
            attl[tid] = 0.f;
        }
    }
    __syncthreads();

    int w = tid >> 6, lane = tid & 63;
    int row16 = lane & 15;
    int kq = lane >> 4;
    int k0 = kq << 3;
    f32x4 acc[8];
    for (int j = 0; j < 8; ++j) acc[j] = (f32x4){0.f, 0.f, 0.f, 0.f};

    int v = vbase + w * 16 + row16;
    if (v >= V_VIEWS) v = V_VIEWS - 1;            // att=0 handles padding
    const float* xp = x_mod + (size_t)v * IN_MOD;

#pragma unroll
    for (int kk = 0; kk < 4; ++kk) {
        float4 x0 = *(const float4*)(xp + kk * 32 + k0);
        float4 x1 = *(const float4*)(xp + kk * 32 + k0 + 4);
        bf16x8 a;
        a[0] = f2bf(x0.x); a[1] = f2bf(x0.y); a[2] = f2bf(x0.z); a[3] = f2bf(x0.w);
        a[4] = f2bf(x1.x); a[5] = f2bf(x1.y); a[6] = f2bf(x1.z); a[7] = f2bf(x1.w);
        const bf16x8* wf = (const bf16x8*)(Wf + ((size_t)(kk * 8) * 64 + lane) * 8);
#pragma unroll
        for (int j = 0; j < 8; ++j) {
            bf16x8 b = wf[j * 64];
            acc[j] = __builtin_amdgcn_mfma_f32_16x16x32_bf16(a, b, acc[j], 0, 0, 0);
        }
    }
#pragma unroll
    for (int j = 0; j < 8; ++j) {
        int ch = j * 16 + row16;
        int rbase = w * 16 + (kq << 2);
#pragma unroll
        for (int r = 0; r < 4; ++r) {
            int rw = rbase + r;
            Yl[rw * 132 + ch] = fmaxf(acc[j][r], 0.f) * attl[rw];
        }
    }
    __syncthreads();
    if (tid < IN_MOD) {
        int c = tid;
        float s_acc = 0.f;
        int cur = didxl[0];
        for (int r = 0; r < VB; ++r) {
            int s = didxl[r];
            if (s != cur) {
                if (csr[cur] >= vbase && csr[cur + 1] <= vbase + VB)
                    pooled[(size_t)cur * IN_MOD + c] = s_acc;
                else
                    atomicAdd(&pooled[(size_t)cur * IN_MOD + c], s_acc);
                s_acc = 0.f; cur = s;
            }
            s_acc += Yl[r * 132 + c];
        }
        if (csr[cur] >= vbase && csr[cur + 1] <= vbase + VB)
            pooled[(size_t)cur * IN_MOD + c] = s_acc;
        else
            atomicAdd(&pooled[(size_t)cur * IN_MOD + c], s_acc);
    }
}

// ---------------- kD: out = (pooled @ Wmod2) * gate, in place [bf16 MFMA]; x_seen ----------------
__global__ __launch_bounds__(256) void kD_final(
    const short* __restrict__ W2f,
    const float* __restrict__ segmax, const int* __restrict__ csr,
    const float* __restrict__ g_w, const float* __restrict__ g_b,
    float* __restrict__ out) {
    int tid = threadIdx.x;
    int w = tid >> 6, lane = tid & 63;
    int row16 = lane & 15;
    int kq = lane >> 4;
    int k0 = kq << 3;
    int rbase = blockIdx.x * 64 + w * 16;
    float gw = g_w[0], gb = g_b[0];

    int rr = rbase + row16;
    if (rr >= N_PTS) rr = N_PTS - 1;              // clamped read; writes masked below
    const float* xp = out + (size_t)rr * IN_MOD;

    f32x4 acc[8];
    for (int j = 0; j < 8; ++j) acc[j] = (f32x4){0.f, 0.f, 0.f, 0.f};
#pragma unroll
    for (int kk = 0; kk < 4; ++kk) {
        float4 x0 = *(const float4*)(xp + kk * 32 + k0);
        float4 x1 = *(const float4*)(xp + kk * 32 + k0 + 4);
        bf16x8 a;
        a[0] = f2bf(x0.x); a[1] = f2bf(x0.y); a[2] = f2bf(x0.z); a[3] = f2bf(x0.w);
        a[4] = f2bf(x1.x); a[5] = f2bf(x1.y); a[6] = f2bf(x1.z); a[7] = f2bf(x1.w);
        const bf16x8* wf = (const bf16x8*)(W2f + ((size_t)(kk * 8) * 64 + lane) * 8);
#pragma unroll
        for (int j = 0; j < 8; ++j) {
            bf16x8 b = wf[j * 64];
            acc[j] = __builtin_amdgcn_mfma_f32_16x16x32_bf16(a, b, acc[j], 0, 0, 0);
        }
    }
    float gate[4];
    int rowv[4];
#pragma unroll
    for (int r = 0; r < 4; ++r) {
        int ro = rbase + (kq << 2) + r;
        rowv[r] = ro;
        if (ro < N_PTS) {
            bool nz = csr[ro + 1] > csr[ro];
            float gin = nz ? segmax[ro] : 0.f;
            gate[r] = tanhf(fmaxf(gw * gin + gb, 0.f));
            if (row16 == 0) out[(size_t)N_PTS * IN_MOD + ro] = nz ? 1.f : 0.f;
        } else {
            gate[r] = 0.f;
        }
    }
#pragma unroll
    for (int j = 0; j < 8; ++j) {
        int ch = j * 16 + row16;
#pragma unroll
        for (int r = 0; r < 4; ++r) {
            if (rowv[r] < N_PTS)
                out[(size_t)rowv[r] * IN_MOD + ch] = acc[j][r] * gate[r];
        }
    }
}

extern "C" void kernel_launch(void* const* d_in, const int* in_sizes, int n_in,
                              void* d_out, int out_size, void* d_ws, size_t ws_size,
                              hipStream_t stream) {
    (void)in_sizes; (void)n_in; (void)out_size; (void)ws_size;
    const float* x_main = (const float*)d_in[0];
    const float* x_mod  = (const float*)d_in[1];
    const float* x_map  = (const float*)d_in[2];
    const int*   csr    = (const int*)d_in[3];
    const float* W_main1 = (const float*)d_in[4];
    const float* W_main2 = (const float*)d_in[5];
    const float* W_map1  = (const float*)d_in[6];
    const float* W_map2  = (const float*)d_in[7];
    const float* W_mod1  = (const float*)d_in[8];
    const float* W_mod2  = (const float*)d_in[9];
    const float* WQ = (const float*)d_in[10];
    const float* bQ = (const float*)d_in[11];
    const float* WK = (const float*)d_in[12];
    const float* bK = (const float*)d_in[13];
    const float* g_w = (const float*)d_in[14];
    const float* g_b = (const float*)d_in[15];
    float* out = (float*)d_out;

    char* ws = (char*)d_ws;
    int*   didx   = (int*)ws;                       // [ 0.0,  2.0 MB)
    float* wq     = (float*)(ws + 2000000);         // [ 2.0,  8.4 MB)
    float* qb     = (float*)(ws + 8400000);         // [ 8.4,  8.6 MB)
    float* ctxw   = (float*)(ws + 8600000);         // [ 8.6, 15.0 MB)  ctxbits -> ctxW2b
    float* comp   = (float*)(ws + 15000000);        // [15.0, 17.0 MB)  comp -> att
    float* segmax = (float*)(ws + 17000000);        // [17.0, 17.2 MB)
    short* Wf     = (short*)(ws + 17200000);        // 32 KB
    short* W1f    = (short*)(ws + 17240000);        // 2 KB
    short* W2af   = (short*)(ws + 17244000);        // 2 KB
    short* W2f    = (short*)(ws + 17248000);        // 32 KB
    float* pooled = out;

    k0_setup<<<512, 256, 0, stream>>>(csr, W_mod1, W_mod2, W_map1, W_map2,
                                      didx, pooled, ctxw, Wf, W1f, W2af, W2f);
    kA_main_q<<<(N_PTS + 7) / 8, 256, 0, stream>>>(x_main, W_main1, W_main2, WQ, bQ,
                                                   WK, bK, wq, qb);
    kH_ctx<<<(V_VIEWS + 63) / 64, 256, 0, stream>>>(x_map, didx, W1f, (int*)ctxw);
    kB2b_ctxw<<<(N_PTS + 7) / 8, 256, 0, stream>>>(W_map2, ctxw);
    kB3_comp<<<(V_VIEWS + 63) / 64, 256, 0, stream>>>(x_map, didx, W1f, W2af,
                                                      ctxw, wq, qb, comp);
    kB4_att<<<(N_PTS + 3) / 4, 256, 0, stream>>>(comp, csr, segmax);
    kC_pool<<<(V_VIEWS + VB - 1) / VB, 256, 0, stream>>>(x_mod, Wf, didx, csr,
                                                         comp, pooled);
    kD_final<<<(N_PTS + 63) / 64, 256, 0, stream>>>(W2f, segmax, csr, g_w, g_b, out);
}